// Round 1
// 2374.345 us; speedup vs baseline: 1.2957x; 1.2957x over previous
//
#include <hip/hip_runtime.h>
#include <hip/hip_cooperative_groups.h>

namespace cg = cooperative_groups;

typedef unsigned short u16;
typedef unsigned int   u32;
typedef __attribute__((ext_vector_type(8))) short short8;  // 8 bf16 (4 VGPRs) MFMA frag
typedef __attribute__((ext_vector_type(4))) float f32x4;   // MFMA 16x16 accumulator

#define B_   16
#define S_   128
#define H_   1024
#define E_   512
#define V_   32000

static __device__ __forceinline__ float bf2f(u16 x){
  u32 u = ((u32)x) << 16; float f; __builtin_memcpy(&f, &u, 4); return f;
}
static __device__ __forceinline__ u16 f2bf(float f){
  u32 u; __builtin_memcpy(&u, &f, 4);
  u += 0x7fffu + ((u >> 16) & 1u);           // round-to-nearest-even
  return (u16)(u >> 16);
}
static __device__ __forceinline__ void gl2lds16(const void* g, void* l){
  // async global->LDS, 16B/lane; LDS dest = wave-uniform base + lane*16
  __builtin_amdgcn_global_load_lds((const __attribute__((address_space(1))) u32*)g,
                                   (__attribute__((address_space(3))) u32*)l, 16, 0, 0);
}
static __device__ __forceinline__ float sigm(float x){ return 1.0f/(1.0f + __expf(-x)); }
static __device__ __forceinline__ float tanh_f(float x){
  float a = fabsf(x);
  float e = __expf(-2.0f*a);
  float r = (1.0f - e)/(1.0f + e);           // e<=1 always: no inf/NaN
  return x < 0.0f ? -r : r;
}
// dtype-agnostic scalar load (element index i)
static __device__ __forceinline__ float ldf(const void* base, long i, int is32){
  return is32 ? ((const float*)base)[i] : bf2f(((const u16*)base)[i]);
}
// dtype-agnostic 8-element load -> packed bf16 (i must be 8-aligned)
static __device__ __forceinline__ short8 load8(const void* base, long i, int is32){
  short8 r;
  if (is32){
    const float* p = (const float*)base + i;
    f32x4 a = *(const f32x4*)p;
    f32x4 b = *(const f32x4*)(p + 4);
    r[0]=(short)f2bf(a[0]); r[1]=(short)f2bf(a[1]);
    r[2]=(short)f2bf(a[2]); r[3]=(short)f2bf(a[3]);
    r[4]=(short)f2bf(b[0]); r[5]=(short)f2bf(b[1]);
    r[6]=(short)f2bf(b[2]); r[7]=(short)f2bf(b[3]);
  } else {
    r = *(const short8*)((const u16*)base + i);
  }
  return r;
}

// ---------------------------------------------------------------------------
// dtype sniff on h ~ N(0,1): for bf16 data, every u32's bits[7:14] are a bf16
// exponent field (in [100,140] essentially always); for fp32 data they are
// uniform mantissa bits (~16% in range). 1024 words, majority vote.
// ---------------------------------------------------------------------------
__global__ void k_detect(const u32* __restrict__ h32, u32* __restrict__ flag){
  const int lane = threadIdx.x;        // 64
  int cnt = 0;
  for (int i = 0; i < 16; ++i){
    u32 w = h32[lane*16 + i];
    u32 e = (w >> 7) & 0xFFu;
    cnt += (e >= 100u && e <= 140u) ? 1 : 0;
  }
  for (int off = 32; off; off >>= 1) cnt += __shfl_down(cnt, off, 64);
  if (lane == 0) flag[0] = (cnt < 512) ? 1u : 0u;   // 1 = fp32 inputs/outputs
}

// ---------------------------------------------------------------------------
// Phase A: xg[t][q][r][b] (fp32) = emb[tgt[b][t]] . W_ih[g=q*1024+r] + b_ih + b_hh
// M-tile 64 tokens (token m = t*16+b), N-tile 64 gates, K=512, BK=32.
// ---------------------------------------------------------------------------
__global__ __launch_bounds__(256) void k_xg(
    const int* __restrict__ tgt, const void* __restrict__ emb,
    const void* __restrict__ W_ih, const void* __restrict__ b_ih,
    const void* __restrict__ b_hh, float* __restrict__ xg,
    const u32* __restrict__ flag)
{
  const int is32 = (int)flag[0];
  __shared__ __align__(16) u16 la[64*32];
  __shared__ __align__(16) u16 lb[64*32];
  __shared__ int ids[64];
  const int nb = blockIdx.x;           // gate block   (64)
  const int mb = blockIdx.y;           // token block  (32)
  const int tid = threadIdx.x, lane = tid & 63, wv = tid >> 6;
  const int wm = wv >> 1, wn = wv & 1; // 2x2 wave grid, wave tile 32x32
  const int g0 = nb*64;

  if (tid < 64){
    int m = mb*64 + tid;               // token; t = m>>4, b = m&15; tgt is [B][S]
    ids[tid] = tgt[(m & 15)*S_ + (m >> 4)];
  }
  __syncthreads();

  f32x4 acc[2][2];
#pragma unroll
  for (int i = 0; i < 2; ++i)
#pragma unroll
    for (int j = 0; j < 2; ++j) acc[i][j] = (f32x4){0.f,0.f,0.f,0.f};

  const int srow = tid >> 2, sk = (tid & 3)*8;   // 64 rows x 4 loaders of 8
  const long arow = (long)ids[srow]*E_ + sk;
  const long brow = (long)(g0 + srow)*E_ + sk;

  for (int k0 = 0; k0 < E_; k0 += 32){
    short8 va = load8(emb,  arow + k0, is32);
    short8 vb = load8(W_ih, brow + k0, is32);
    *(short8*)&la[srow*32 + sk] = va;
    *(short8*)&lb[srow*32 + sk] = vb;
    __syncthreads();
    short8 af[2], bfv[2];
#pragma unroll
    for (int mt = 0; mt < 2; ++mt)
      af[mt] = *(const short8*)&la[(wm*32 + mt*16 + (lane & 15))*32 + ((lane >> 4)*8)];
#pragma unroll
    for (int nt = 0; nt < 2; ++nt)
      bfv[nt] = *(const short8*)&lb[(wn*32 + nt*16 + (lane & 15))*32 + ((lane >> 4)*8)];
#pragma unroll
    for (int mt = 0; mt < 2; ++mt)
#pragma unroll
      for (int nt = 0; nt < 2; ++nt)
        acc[mt][nt] = __builtin_amdgcn_mfma_f32_16x16x32_bf16(af[mt], bfv[nt], acc[mt][nt], 0,0,0);
    __syncthreads();
  }

  // epilogue: C rows = token-in-tile (batch within), cols = gate
  const int col = lane & 15, quad = lane >> 4;
#pragma unroll
  for (int nt = 0; nt < 2; ++nt){
    int g = g0 + wn*32 + nt*16 + col;
    float bias = ldf(b_ih, g, is32) + ldf(b_hh, g, is32);
    int q = g >> 10, r = g & 1023;
#pragma unroll
    for (int mt = 0; mt < 2; ++mt){
      int t = mb*4 + wm*2 + mt;
      f32x4 v;
      v[0] = acc[mt][nt][0] + bias;
      v[1] = acc[mt][nt][1] + bias;
      v[2] = acc[mt][nt][2] + bias;
      v[3] = acc[mt][nt][3] + bias;
      *(f32x4*)(xg + ((long)((t*4 + q)*1024 + r)*16 + quad*4)) = v;
    }
  }
}

// ---------------------------------------------------------------------------
// Phase B (persistent): ALL 128 timesteps in ONE cooperative dispatch.
// 64 WGs x 256 threads; WG s owns hidden units [s*16, s*16+16) for all batches.
// W_hh fragments loaded ONCE into 128 VGPRs/thread and held across the loop
// (previously: re-fetched 16.8 MB from L2/L3 every step = 2.1 GB/iter).
// c is thread-private -> lives in a register for the whole sequence.
// Only h (128 KB ping-pong, L2-resident) crosses WGs, via grid.sync().
// ---------------------------------------------------------------------------
__global__ __launch_bounds__(256, 1) void k_steps_all(
    const void* __restrict__ W_hh, const float* __restrict__ xg,
    const void* __restrict__ h_in, const void* __restrict__ c_in,
    u16* __restrict__ h_buf, u16* __restrict__ hs,
    const u32* __restrict__ flag)
{
  const int is32 = (int)flag[0];
  const int s    = blockIdx.x;         // 64
  const int tid  = threadIdx.x;
  const int lane = tid & 63;
  const int wv   = tid >> 6;           // wave -> K slice [wv*256, wv*256+256)

  __shared__ __align__(16) float part[4][4][16][20];  // [wave][gate][r][b pad20]

  // B-operand fragments: rows q*1024 + s*16 + (lane&15), k = wv*256 + quad*8 + j*32
  short8 wf[4][8];
#pragma unroll
  for (int q = 0; q < 4; ++q){
    const long wrow = (long)(q*H_ + s*16 + (lane & 15))*H_ + wv*256 + ((lane >> 4)*8);
#pragma unroll
    for (int j = 0; j < 8; ++j)
      wf[q][j] = load8(W_hh, wrow + j*32, is32);
  }

  // epilogue ownership: thread -> (batch eb, hidden unit s*16+er)
  const int eb = tid >> 4;
  const int er = tid & 15;
  const int co = eb*H_ + s*16 + er;
  float c_val = ldf(c_in, co, is32);   // carry lives in a register

  const int arow = (lane & 15)*H_ + wv*256 + ((lane >> 4)*8);
  const float* xg_b = xg + (s*16 + er)*16 + eb;
  u16* hs_b = hs + (long)eb*S_*H_ + s*16 + er;

  cg::grid_group grid = cg::this_grid();

  // init parity-0 h (hi + lo residual); each WG initializes exactly its slice
  {
    float hv0 = ldf(h_in, co, is32);
    u16 hi0 = f2bf(hv0);
    h_buf[co]          = hi0;
    h_buf[B_*H_ + co]  = f2bf(hv0 - bf2f(hi0));
  }
  grid.sync();

  for (int t = 0; t < S_; ++t){
    // issue xg loads early; latency hides under the h-load + MFMA phase
    const float* xg_t = xg_b + (long)t*65536;
    float pre0 = xg_t[0], pre1 = xg_t[16384], pre2 = xg_t[32768], pre3 = xg_t[49152];

    f32x4 acc[4];
#pragma unroll
    for (int q = 0; q < 4; ++q) acc[q] = (f32x4){0.f,0.f,0.f,0.f};
    const u16* hp = h_buf + (t & 1)*(2*B_*H_) + arow;
#pragma unroll
    for (int j = 0; j < 8; ++j){
      short8 ahi = *(const short8*)(hp + j*32);
      short8 alo = *(const short8*)(hp + B_*H_ + j*32);
#pragma unroll
      for (int q = 0; q < 4; ++q){
        acc[q] = __builtin_amdgcn_mfma_f32_16x16x32_bf16(ahi, wf[q][j], acc[q], 0,0,0);
        acc[q] = __builtin_amdgcn_mfma_f32_16x16x32_bf16(alo, wf[q][j], acc[q], 0,0,0);
      }
    }
#pragma unroll
    for (int q = 0; q < 4; ++q)
      *(f32x4*)&part[wv][q][lane & 15][(lane >> 4)*4] = acc[q];   // [r][b]
    __syncthreads();

    float p0 = pre0, p1 = pre1, p2 = pre2, p3 = pre3;
#pragma unroll
    for (int w = 0; w < 4; ++w){
      p0 += part[w][0][er][eb];
      p1 += part[w][1][er][eb];
      p2 += part[w][2][er][eb];
      p3 += part[w][3][er][eb];
    }
    float iv = sigm(p0), fv = sigm(p1), gv = tanh_f(p2), ov = sigm(p3);
    c_val = fv*c_val + iv*gv;
    float hv = ov*tanh_f(c_val);
    u16 hi = f2bf(hv);
    u16 lo = f2bf(hv - bf2f(hi));      // residual: h error ~2^-17 instead of 2^-9
    const int po = ((t + 1) & 1)*(2*B_*H_);
    h_buf[po + co]          = hi;
    h_buf[po + B_*H_ + co]  = lo;
    hs_b[(long)t*H_] = hi;

    // grid.sync() includes the block barrier, so next iteration's `part`
    // writes cannot race this iteration's reads.
    grid.sync();
  }
}

// ---------------------------------------------------------------------------
// Phase C: logits = hs . W_fc^T + b_fc.  M=2048 (m = b*128+t), N=32000, K=1024.
// A (internal bf16 hs): async gl2lds staging. B (input dtype): load8 staging.
// ---------------------------------------------------------------------------
__global__ __launch_bounds__(256) void k_logits(
    const u16* __restrict__ hs, const void* __restrict__ W_fc,
    const void* __restrict__ b_fc, void* __restrict__ outv,
    const u32* __restrict__ flag)
{
  const int is32 = (int)flag[0];
  __shared__ __align__(16) u16 la[128*32];
  __shared__ __align__(16) u16 lb[128*32];
  const int mb = blockIdx.x;           // 16
  const int nb = blockIdx.y;           // 250
  const int tid = threadIdx.x, lane = tid & 63, wv = tid >> 6;
  const int wm = wv >> 1, wn = wv & 1; // 2x2 wave grid, wave tile 64x64
  const long m0 = (long)mb*128;
  const long n0 = (long)nb*128;

  f32x4 acc[4][4];
#pragma unroll
  for (int i = 0; i < 4; ++i)
#pragma unroll
    for (int j = 0; j < 4; ++j) acc[i][j] = (f32x4){0.f,0.f,0.f,0.f};

  const int srow = lane >> 2, scol = (lane & 3)*8;
  const u16* asrc = hs + (m0 + wv*32 + srow)*H_ + scol;
  u16* lda = &la[wv*32*32];
  const int br = tid >> 2, bk = (tid & 3)*8;     // B rows br and br+64
  const long brow0 = (long)(n0 + br)*H_ + bk;
  const long brow1 = (long)(n0 + br + 64)*H_ + bk;

  for (int k0 = 0; k0 < H_; k0 += 32){
    gl2lds16(asrc + k0,          lda);
    gl2lds16(asrc + 16*H_ + k0,  lda + 16*32);
    *(short8*)&lb[br*32 + bk]        = load8(W_fc, brow0 + k0, is32);
    *(short8*)&lb[(br + 64)*32 + bk] = load8(W_fc, brow1 + k0, is32);
    __syncthreads();
    short8 af[4], bfr[4];
#pragma unroll
    for (int mt = 0; mt < 4; ++mt)
      af[mt] = *(const short8*)&la[(wm*64 + mt*16 + (lane & 15))*32 + ((lane >> 4)*8)];
#pragma unroll
    for (int nt = 0; nt < 4; ++nt)
      bfr[nt] = *(const short8*)&lb[(wn*64 + nt*16 + (lane & 15))*32 + ((lane >> 4)*8)];
#pragma unroll
    for (int mt = 0; mt < 4; ++mt)
#pragma unroll
      for (int nt = 0; nt < 4; ++nt)
        acc[mt][nt] = __builtin_amdgcn_mfma_f32_16x16x32_bf16(af[mt], bfr[nt], acc[mt][nt], 0,0,0);
    __syncthreads();
  }

  const int col = lane & 15, quad = lane >> 4;
#pragma unroll
  for (int nt = 0; nt < 4; ++nt){
    long n = n0 + wn*64 + nt*16 + col;
    float bias = ldf(b_fc, n, is32);
#pragma unroll
    for (int mt = 0; mt < 4; ++mt){
      long m = m0 + wm*64 + mt*16 + quad*4;
      float v0 = acc[mt][nt][0] + bias;
      float v1 = acc[mt][nt][1] + bias;
      float v2 = acc[mt][nt][2] + bias;
      float v3 = acc[mt][nt][3] + bias;
      if (is32){
        float* p = (float*)outv + m*V_ + n;
        p[0] = v0; p[V_] = v1; p[2L*V_] = v2; p[3L*V_] = v3;
      } else {
        u16* p = (u16*)outv + m*V_ + n;
        p[0] = f2bf(v0); p[V_] = f2bf(v1); p[2L*V_] = f2bf(v2); p[3L*V_] = f2bf(v3);
      }
    }
  }
}

// ---------------------------------------------------------------------------
extern "C" void kernel_launch(void* const* d_in, const int* in_sizes, int n_in,
                              void* d_out, int out_size, void* d_ws, size_t ws_size,
                              hipStream_t stream)
{
  (void)in_sizes; (void)n_in; (void)out_size; (void)ws_size;
  const int*  tgt  = (const int*)d_in[0];
  const void* h0   = d_in[1];
  const void* c0   = d_in[2];
  const void* emb  = d_in[3];
  const void* W_ih = d_in[4];
  const void* W_hh = d_in[5];
  const void* b_ih = d_in[6];
  const void* b_hh = d_in[7];
  const void* W_fc = d_in[8];
  const void* b_fc = d_in[9];

  // xg (fp32, 33.5 MB) lives in d_out: dead before k_logits overwrites d_out.
  float* xg = (float*)d_out;
  char* ws    = (char*)d_ws;
  u16*   hs    = (u16*)(ws);             // [16][128][1024] bf16  = 4,194,304 B
  u16*   h_buf = (u16*)(ws + 4194304);   // [2][2][16][1024] bf16 =   131,072 B
  u32*   flag  = (u32*)(ws + 4390912);   // [1] u32: 1 = fp32 I/O

  k_detect<<<1, 64, 0, stream>>>((const u32*)h0, flag);
  dim3 gA(64, 32);
  k_xg<<<gA, 256, 0, stream>>>(tgt, emb, W_ih, b_ih, b_hh, xg, flag);

  // Phase B: one cooperative dispatch for all 128 timesteps.
  u16* hb  = h_buf;
  u16* hsp = hs;
  void* args[7];
  args[0] = (void*)&W_hh;
  args[1] = (void*)&xg;
  args[2] = (void*)&h0;
  args[3] = (void*)&c0;
  args[4] = (void*)&hb;
  args[5] = (void*)&hsp;
  args[6] = (void*)&flag;
  hipLaunchCooperativeKernel((const void*)k_steps_all, dim3(64), dim3(256),
                             args, 0, stream);

  dim3 gC(16, 250);
  k_logits<<<gC, 256, 0, stream>>>(hs, W_fc, b_fc, d_out, flag);
}

// Round 2
// 1897.354 us; speedup vs baseline: 1.6215x; 1.2514x over previous
//
#include <hip/hip_runtime.h>

typedef unsigned short u16;
typedef unsigned int   u32;
typedef unsigned long long u64;
typedef __attribute__((ext_vector_type(8))) short short8;  // 8 bf16 (4 VGPRs) MFMA frag
typedef __attribute__((ext_vector_type(4))) float f32x4;   // MFMA 16x16 accumulator

#define B_   16
#define S_   128
#define H_   1024
#define E_   512
#define V_   32000

static __device__ __forceinline__ float bf2f(u16 x){
  u32 u = ((u32)x) << 16; float f; __builtin_memcpy(&f, &u, 4); return f;
}
static __device__ __forceinline__ u16 f2bf(float f){
  u32 u; __builtin_memcpy(&u, &f, 4);
  u += 0x7fffu + ((u >> 16) & 1u);           // round-to-nearest-even
  return (u16)(u >> 16);
}
static __device__ __forceinline__ void gl2lds16(const void* g, void* l){
  // async global->LDS, 16B/lane; LDS dest = wave-uniform base + lane*16
  __builtin_amdgcn_global_load_lds((const __attribute__((address_space(1))) u32*)g,
                                   (__attribute__((address_space(3))) u32*)l, 16, 0, 0);
}
static __device__ __forceinline__ float sigm(float x){ return 1.0f/(1.0f + __expf(-x)); }
static __device__ __forceinline__ float tanh_f(float x){
  float a = fabsf(x);
  float e = __expf(-2.0f*a);
  float r = (1.0f - e)/(1.0f + e);           // e<=1 always: no inf/NaN
  return x < 0.0f ? -r : r;
}
// dtype-agnostic scalar load (element index i)
static __device__ __forceinline__ float ldf(const void* base, long i, int is32){
  return is32 ? ((const float*)base)[i] : bf2f(((const u16*)base)[i]);
}
// dtype-agnostic 8-element load -> packed bf16 (i must be 8-aligned)
static __device__ __forceinline__ short8 load8(const void* base, long i, int is32){
  short8 r;
  if (is32){
    const float* p = (const float*)base + i;
    f32x4 a = *(const f32x4*)p;
    f32x4 b = *(const f32x4*)(p + 4);
    r[0]=(short)f2bf(a[0]); r[1]=(short)f2bf(a[1]);
    r[2]=(short)f2bf(a[2]); r[3]=(short)f2bf(a[3]);
    r[4]=(short)f2bf(b[0]); r[5]=(short)f2bf(b[1]);
    r[6]=(short)f2bf(b[2]); r[7]=(short)f2bf(b[3]);
  } else {
    r = *(const short8*)((const u16*)base + i);
  }
  return r;
}

// device-coherent (agent-scope) accessors for the h ping-pong buffer.
// Loads bypass stale L1/L2; stores write through to the coherence point.
static __device__ __forceinline__ short8 ld_frag_dev(const u16* p){
  u64 a = __hip_atomic_load((const u64*)p,       __ATOMIC_RELAXED, __HIP_MEMORY_SCOPE_AGENT);
  u64 b = __hip_atomic_load((const u64*)(p + 4), __ATOMIC_RELAXED, __HIP_MEMORY_SCOPE_AGENT);
  short8 r;
  __builtin_memcpy(&r, &a, 8);
  __builtin_memcpy((char*)&r + 8, &b, 8);
  return r;
}
static __device__ __forceinline__ void st_dev_u16(u16* p, u16 v){
  __hip_atomic_store(p, v, __ATOMIC_RELAXED, __HIP_MEMORY_SCOPE_AGENT);
}

// ---------------------------------------------------------------------------
// dtype sniff on h ~ N(0,1); also zeroes the inter-WG barrier state.
// ---------------------------------------------------------------------------
__global__ void k_detect(const u32* __restrict__ h32, u32* __restrict__ flag,
                         u32* __restrict__ bar_cnt, u32* __restrict__ bar_gen){
  const int lane = threadIdx.x;        // 64
  int cnt = 0;
  for (int i = 0; i < 16; ++i){
    u32 w = h32[lane*16 + i];
    u32 e = (w >> 7) & 0xFFu;
    cnt += (e >= 100u && e <= 140u) ? 1 : 0;
  }
  for (int off = 32; off; off >>= 1) cnt += __shfl_down(cnt, off, 64);
  if (lane == 0){
    flag[0] = (cnt < 512) ? 1u : 0u;   // 1 = fp32 inputs/outputs
    __hip_atomic_store(bar_cnt, 0u, __ATOMIC_RELAXED, __HIP_MEMORY_SCOPE_AGENT);
    __hip_atomic_store(bar_gen, 0u, __ATOMIC_RELAXED, __HIP_MEMORY_SCOPE_AGENT);
  }
}

// ---------------------------------------------------------------------------
// Phase A: xg[t][q][r][b] (fp32) = emb[tgt[b][t]] . W_ih[g=q*1024+r] + b_ih + b_hh
// ---------------------------------------------------------------------------
__global__ __launch_bounds__(256) void k_xg(
    const int* __restrict__ tgt, const void* __restrict__ emb,
    const void* __restrict__ W_ih, const void* __restrict__ b_ih,
    const void* __restrict__ b_hh, float* __restrict__ xg,
    const u32* __restrict__ flag)
{
  const int is32 = (int)flag[0];
  __shared__ __align__(16) u16 la[64*32];
  __shared__ __align__(16) u16 lb[64*32];
  __shared__ int ids[64];
  const int nb = blockIdx.x;           // gate block   (64)
  const int mb = blockIdx.y;           // token block  (32)
  const int tid = threadIdx.x, lane = tid & 63, wv = tid >> 6;
  const int wm = wv >> 1, wn = wv & 1; // 2x2 wave grid, wave tile 32x32
  const int g0 = nb*64;

  if (tid < 64){
    int m = mb*64 + tid;               // token; t = m>>4, b = m&15; tgt is [B][S]
    ids[tid] = tgt[(m & 15)*S_ + (m >> 4)];
  }
  __syncthreads();

  f32x4 acc[2][2];
#pragma unroll
  for (int i = 0; i < 2; ++i)
#pragma unroll
    for (int j = 0; j < 2; ++j) acc[i][j] = (f32x4){0.f,0.f,0.f,0.f};

  const int srow = tid >> 2, sk = (tid & 3)*8;   // 64 rows x 4 loaders of 8
  const long arow = (long)ids[srow]*E_ + sk;
  const long brow = (long)(g0 + srow)*E_ + sk;

  for (int k0 = 0; k0 < E_; k0 += 32){
    short8 va = load8(emb,  arow + k0, is32);
    short8 vb = load8(W_ih, brow + k0, is32);
    *(short8*)&la[srow*32 + sk] = va;
    *(short8*)&lb[srow*32 + sk] = vb;
    __syncthreads();
    short8 af[2], bfv[2];
#pragma unroll
    for (int mt = 0; mt < 2; ++mt)
      af[mt] = *(const short8*)&la[(wm*32 + mt*16 + (lane & 15))*32 + ((lane >> 4)*8)];
#pragma unroll
    for (int nt = 0; nt < 2; ++nt)
      bfv[nt] = *(const short8*)&lb[(wn*32 + nt*16 + (lane & 15))*32 + ((lane >> 4)*8)];
#pragma unroll
    for (int mt = 0; mt < 2; ++mt)
#pragma unroll
      for (int nt = 0; nt < 2; ++nt)
        acc[mt][nt] = __builtin_amdgcn_mfma_f32_16x16x32_bf16(af[mt], bfv[nt], acc[mt][nt], 0,0,0);
    __syncthreads();
  }

  // epilogue: C rows = token-in-tile (batch within), cols = gate
  const int col = lane & 15, quad = lane >> 4;
#pragma unroll
  for (int nt = 0; nt < 2; ++nt){
    int g = g0 + wn*32 + nt*16 + col;
    float bias = ldf(b_ih, g, is32) + ldf(b_hh, g, is32);
    int q = g >> 10, r = g & 1023;
#pragma unroll
    for (int mt = 0; mt < 2; ++mt){
      int t = mb*4 + wm*2 + mt;
      f32x4 v;
      v[0] = acc[mt][nt][0] + bias;
      v[1] = acc[mt][nt][1] + bias;
      v[2] = acc[mt][nt][2] + bias;
      v[3] = acc[mt][nt][3] + bias;
      *(f32x4*)(xg + ((long)((t*4 + q)*1024 + r)*16 + quad*4)) = v;
    }
  }
}

// ---------------------------------------------------------------------------
// Phase B (persistent): ALL 128 timesteps, ONE cooperative dispatch, but with a
// LIGHTWEIGHT split arrive/wait barrier instead of cg::grid.sync() (which
// brackets every step with L2 writeback+invalidate across 8 XCDs -> 12.7us/step
// measured).  Coherence is narrowed to the 128KB h ping-pong: h is accessed
// ONLY via agent-scope atomics (sc1 write-through stores, L1/L2-bypassing
// loads), so the barrier itself is just one fetch_add + spin per WG.
// W_hh lives in VGPRs across the whole loop; c is a thread-private register.
// ---------------------------------------------------------------------------
__global__ __launch_bounds__(256, 1) void k_steps_all(
    const void* __restrict__ W_hh, const float* __restrict__ xg,
    const void* __restrict__ h_in, const void* __restrict__ c_in,
    u16* __restrict__ h_buf, u16* __restrict__ hs,
    const u32* __restrict__ flag, u32* bar_cnt, u32* bar_gen)
{
  const int is32 = (int)flag[0];
  const int s    = blockIdx.x;         // 64
  const int tid  = threadIdx.x;
  const int lane = tid & 63;
  const int wv   = tid >> 6;           // wave -> K slice [wv*256, wv*256+256)

  __shared__ __align__(16) float part[4][4][16][20];  // [wave][gate][r][b pad20]

  // B-operand fragments: rows q*1024 + s*16 + (lane&15), k = wv*256 + quad*8 + j*32
  short8 wf[4][8];
#pragma unroll
  for (int q = 0; q < 4; ++q){
    const long wrow = (long)(q*H_ + s*16 + (lane & 15))*H_ + wv*256 + ((lane >> 4)*8);
#pragma unroll
    for (int j = 0; j < 8; ++j)
      wf[q][j] = load8(W_hh, wrow + j*32, is32);
  }

  // epilogue ownership: thread -> (batch eb, hidden unit s*16+er)
  const int eb = tid >> 4;
  const int er = tid & 15;
  const int co = eb*H_ + s*16 + er;
  float c_val = ldf(c_in, co, is32);   // carry lives in a register

  const int arow = (lane & 15)*H_ + wv*256 + ((lane >> 4)*8);
  const float* xg_b = xg + (s*16 + er)*16 + eb;
  u16* hs_b = hs + (long)eb*S_*H_ + s*16 + er;

  // init parity-0 h (hi + lo residual); each WG initializes exactly its slice
  {
    float hv0 = ldf(h_in, co, is32);
    u16 hi0 = f2bf(hv0);
    st_dev_u16(h_buf + co,         hi0);
    st_dev_u16(h_buf + B_*H_ + co, f2bf(hv0 - bf2f(hi0)));
  }
  // arrive #1
  __syncthreads();                     // drains vmcnt: h stores are device-visible
  if (tid == 0){
    u32 old = __hip_atomic_fetch_add(bar_cnt, 1u, __ATOMIC_ACQ_REL, __HIP_MEMORY_SCOPE_AGENT);
    if (old == 63u){
      __hip_atomic_store(bar_cnt, 0u, __ATOMIC_RELAXED, __HIP_MEMORY_SCOPE_AGENT);
      __hip_atomic_store(bar_gen, 1u, __ATOMIC_RELEASE, __HIP_MEMORY_SCOPE_AGENT);
    }
  }

  for (int t = 0; t < S_; ++t){
    // xg prefetch issued BEFORE the wait: latency hides under the spin
    const float* xg_t = xg_b + (long)t*65536;
    float pre0 = xg_t[0], pre1 = xg_t[16384], pre2 = xg_t[32768], pre3 = xg_t[49152];

    // wait(t+1): all WGs have published h for parity t&1
    if (tid == 0){
      while (__hip_atomic_load(bar_gen, __ATOMIC_ACQUIRE, __HIP_MEMORY_SCOPE_AGENT) < (u32)(t + 1))
        __builtin_amdgcn_s_sleep(1);
    }
    __syncthreads();

    f32x4 acc[4];
#pragma unroll
    for (int q = 0; q < 4; ++q) acc[q] = (f32x4){0.f,0.f,0.f,0.f};
    const u16* hp = h_buf + (t & 1)*(2*B_*H_) + arow;
#pragma unroll
    for (int j = 0; j < 8; ++j){
      short8 ahi = ld_frag_dev(hp + j*32);
      short8 alo = ld_frag_dev(hp + B_*H_ + j*32);
#pragma unroll
      for (int q = 0; q < 4; ++q){
        acc[q] = __builtin_amdgcn_mfma_f32_16x16x32_bf16(ahi, wf[q][j], acc[q], 0,0,0);
        acc[q] = __builtin_amdgcn_mfma_f32_16x16x32_bf16(alo, wf[q][j], acc[q], 0,0,0);
      }
    }
#pragma unroll
    for (int q = 0; q < 4; ++q)
      *(f32x4*)&part[wv][q][lane & 15][(lane >> 4)*4] = acc[q];   // [r][b]
    __syncthreads();

    float p0 = pre0, p1 = pre1, p2 = pre2, p3 = pre3;
#pragma unroll
    for (int w = 0; w < 4; ++w){
      p0 += part[w][0][er][eb];
      p1 += part[w][1][er][eb];
      p2 += part[w][2][er][eb];
      p3 += part[w][3][er][eb];
    }
    float iv = sigm(p0), fv = sigm(p1), gv = tanh_f(p2), ov = sigm(p3);
    c_val = fv*c_val + iv*gv;
    float hv = ov*tanh_f(c_val);
    u16 hi = f2bf(hv);
    u16 lo = f2bf(hv - bf2f(hi));      // residual: h error ~2^-17 instead of 2^-9
    const int po = ((t + 1) & 1)*(2*B_*H_);
    st_dev_u16(h_buf + po + co,         hi);
    st_dev_u16(h_buf + po + B_*H_ + co, lo);
    hs_b[(long)t*H_] = hi;

    // arrive(t+2).  Parity X written at step t is re-read at step t+2: the two
    // intervening arrive/wait pairs give the same separation grid.sync() did.
    __syncthreads();                   // part reads done + h stores drained
    if (tid == 0){
      u32 old = __hip_atomic_fetch_add(bar_cnt, 1u, __ATOMIC_ACQ_REL, __HIP_MEMORY_SCOPE_AGENT);
      if (old == 63u){
        __hip_atomic_store(bar_cnt, 0u, __ATOMIC_RELAXED, __HIP_MEMORY_SCOPE_AGENT);
        __hip_atomic_store(bar_gen, (u32)(t + 2), __ATOMIC_RELEASE, __HIP_MEMORY_SCOPE_AGENT);
      }
    }
  }
}

// ---------------------------------------------------------------------------
// Phase C: logits = hs . W_fc^T + b_fc.  M=2048 (m = b*128+t), N=32000, K=1024.
// Output stores are non-temporal: the 262MB logits stream was thrashing W_fc
// out of L3 (FETCH_SIZE 525MB vs 135MB ideal).
// ---------------------------------------------------------------------------
__global__ __launch_bounds__(256) void k_logits(
    const u16* __restrict__ hs, const void* __restrict__ W_fc,
    const void* __restrict__ b_fc, void* __restrict__ outv,
    const u32* __restrict__ flag)
{
  const int is32 = (int)flag[0];
  __shared__ __align__(16) u16 la[128*32];
  __shared__ __align__(16) u16 lb[128*32];
  const int mb = blockIdx.x;           // 16
  const int nb = blockIdx.y;           // 250
  const int tid = threadIdx.x, lane = tid & 63, wv = tid >> 6;
  const int wm = wv >> 1, wn = wv & 1; // 2x2 wave grid, wave tile 64x64
  const long m0 = (long)mb*128;
  const long n0 = (long)nb*128;

  f32x4 acc[4][4];
#pragma unroll
  for (int i = 0; i < 4; ++i)
#pragma unroll
    for (int j = 0; j < 4; ++j) acc[i][j] = (f32x4){0.f,0.f,0.f,0.f};

  const int srow = lane >> 2, scol = (lane & 3)*8;
  const u16* asrc = hs + (m0 + wv*32 + srow)*H_ + scol;
  u16* lda = &la[wv*32*32];
  const int br = tid >> 2, bk = (tid & 3)*8;     // B rows br and br+64
  const long brow0 = (long)(n0 + br)*H_ + bk;
  const long brow1 = (long)(n0 + br + 64)*H_ + bk;

  for (int k0 = 0; k0 < H_; k0 += 32){
    gl2lds16(asrc + k0,          lda);
    gl2lds16(asrc + 16*H_ + k0,  lda + 16*32);
    *(short8*)&lb[br*32 + bk]        = load8(W_fc, brow0 + k0, is32);
    *(short8*)&lb[(br + 64)*32 + bk] = load8(W_fc, brow1 + k0, is32);
    __syncthreads();
    short8 af[4], bfr[4];
#pragma unroll
    for (int mt = 0; mt < 4; ++mt)
      af[mt] = *(const short8*)&la[(wm*64 + mt*16 + (lane & 15))*32 + ((lane >> 4)*8)];
#pragma unroll
    for (int nt = 0; nt < 4; ++nt)
      bfr[nt] = *(const short8*)&lb[(wn*64 + nt*16 + (lane & 15))*32 + ((lane >> 4)*8)];
#pragma unroll
    for (int mt = 0; mt < 4; ++mt)
#pragma unroll
      for (int nt = 0; nt < 4; ++nt)
        acc[mt][nt] = __builtin_amdgcn_mfma_f32_16x16x32_bf16(af[mt], bfr[nt], acc[mt][nt], 0,0,0);
    __syncthreads();
  }

  const int col = lane & 15, quad = lane >> 4;
#pragma unroll
  for (int nt = 0; nt < 4; ++nt){
    long n = n0 + wn*64 + nt*16 + col;
    float bias = ldf(b_fc, n, is32);
#pragma unroll
    for (int mt = 0; mt < 4; ++mt){
      long m = m0 + wm*64 + mt*16 + quad*4;
      float v0 = acc[mt][nt][0] + bias;
      float v1 = acc[mt][nt][1] + bias;
      float v2 = acc[mt][nt][2] + bias;
      float v3 = acc[mt][nt][3] + bias;
      if (is32){
        float* p = (float*)outv + m*V_ + n;
        __builtin_nontemporal_store(v0, p);
        __builtin_nontemporal_store(v1, p + V_);
        __builtin_nontemporal_store(v2, p + 2L*V_);
        __builtin_nontemporal_store(v3, p + 3L*V_);
      } else {
        u16* p = (u16*)outv + m*V_ + n;
        __builtin_nontemporal_store(f2bf(v0), p);
        __builtin_nontemporal_store(f2bf(v1), p + V_);
        __builtin_nontemporal_store(f2bf(v2), p + 2L*V_);
        __builtin_nontemporal_store(f2bf(v3), p + 3L*V_);
      }
    }
  }
}

// ---------------------------------------------------------------------------
extern "C" void kernel_launch(void* const* d_in, const int* in_sizes, int n_in,
                              void* d_out, int out_size, void* d_ws, size_t ws_size,
                              hipStream_t stream)
{
  (void)in_sizes; (void)n_in; (void)out_size; (void)ws_size;
  const int*  tgt  = (const int*)d_in[0];
  const void* h0   = d_in[1];
  const void* c0   = d_in[2];
  const void* emb  = d_in[3];
  const void* W_ih = d_in[4];
  const void* W_hh = d_in[5];
  const void* b_ih = d_in[6];
  const void* b_hh = d_in[7];
  const void* W_fc = d_in[8];
  const void* b_fc = d_in[9];

  // xg (fp32, 33.5 MB) lives in d_out: dead before k_logits overwrites d_out.
  float* xg = (float*)d_out;
  char* ws    = (char*)d_ws;
  u16*   hs    = (u16*)(ws);             // [16][128][1024] bf16  = 4,194,304 B
  u16*   h_buf = (u16*)(ws + 4194304);   // [2][2][16][1024] bf16 =   131,072 B
  u32*   flag  = (u32*)(ws + 4325376);   // [1] u32: 1 = fp32 I/O
  u32*   bcnt  = (u32*)(ws + 4325504);   // barrier arrival counter (own line)
  u32*   bgen  = (u32*)(ws + 4325632);   // barrier generation      (own line)

  k_detect<<<1, 64, 0, stream>>>((const u32*)h0, flag, bcnt, bgen);
  dim3 gA(64, 32);
  k_xg<<<gA, 256, 0, stream>>>(tgt, emb, W_ih, b_ih, b_hh, xg, flag);

  // Phase B: one cooperative dispatch (co-residency guarantee), custom barrier.
  u16* hb  = h_buf;
  u16* hsp = hs;
  void* args[9];
  args[0] = (void*)&W_hh;
  args[1] = (void*)&xg;
  args[2] = (void*)&h0;
  args[3] = (void*)&c0;
  args[4] = (void*)&hb;
  args[5] = (void*)&hsp;
  args[6] = (void*)&flag;
  args[7] = (void*)&bcnt;
  args[8] = (void*)&bgen;
  hipLaunchCooperativeKernel((const void*)k_steps_all, dim3(64), dim3(256),
                             args, 0, stream);

  dim3 gC(16, 250);
  k_logits<<<gC, 256, 0, stream>>>(hs, W_fc, b_fc, d_out, flag);
}

// Round 4
// 1690.974 us; speedup vs baseline: 1.8193x; 1.1220x over previous
//
#include <hip/hip_runtime.h>

typedef unsigned short u16;
typedef unsigned int   u32;
typedef unsigned long long u64;
typedef __attribute__((ext_vector_type(8))) short short8;  // 8 bf16 (4 VGPRs) MFMA frag
typedef __attribute__((ext_vector_type(4))) float f32x4;   // MFMA 16x16 accumulator

#define B_   16
#define S_   128
#define H_   1024
#define E_   512
#define V_   32000

static __device__ __forceinline__ float bf2f(u16 x){
  u32 u = ((u32)x) << 16; float f; __builtin_memcpy(&f, &u, 4); return f;
}
static __device__ __forceinline__ u16 f2bf(float f){
  u32 u; __builtin_memcpy(&u, &f, 4);
  u += 0x7fffu + ((u >> 16) & 1u);           // round-to-nearest-even
  return (u16)(u >> 16);
}
static __device__ __forceinline__ void gl2lds16(const void* g, void* l){
  // async global->LDS, 16B/lane; LDS dest = wave-uniform base + lane*16
  __builtin_amdgcn_global_load_lds((const __attribute__((address_space(1))) u32*)g,
                                   (__attribute__((address_space(3))) u32*)l, 16, 0, 0);
}
static __device__ __forceinline__ float sigm(float x){ return 1.0f/(1.0f + __expf(-x)); }
static __device__ __forceinline__ float tanh_f(float x){
  float a = fabsf(x);
  float e = __expf(-2.0f*a);
  float r = (1.0f - e)/(1.0f + e);           // e<=1 always: no inf/NaN
  return x < 0.0f ? -r : r;
}
// dtype-agnostic scalar load (element index i)
static __device__ __forceinline__ float ldf(const void* base, long i, int is32){
  return is32 ? ((const float*)base)[i] : bf2f(((const u16*)base)[i]);
}
// dtype-agnostic 8-element load -> packed bf16 (i must be 8-aligned)
static __device__ __forceinline__ short8 load8(const void* base, long i, int is32){
  short8 r;
  if (is32){
    const float* p = (const float*)base + i;
    f32x4 a = *(const f32x4*)p;
    f32x4 b = *(const f32x4*)(p + 4);
    r[0]=(short)f2bf(a[0]); r[1]=(short)f2bf(a[1]);
    r[2]=(short)f2bf(a[2]); r[3]=(short)f2bf(a[3]);
    r[4]=(short)f2bf(b[0]); r[5]=(short)f2bf(b[1]);
    r[6]=(short)f2bf(b[2]); r[7]=(short)f2bf(b[3]);
  } else {
    r = *(const short8*)((const u16*)base + i);
  }
  return r;
}

// device-coherent (agent-scope) accessors for the h ping-pong buffer.
static __device__ __forceinline__ short8 ld_frag_dev(const u16* p){
  u64 a = __hip_atomic_load((const u64*)p,       __ATOMIC_RELAXED, __HIP_MEMORY_SCOPE_AGENT);
  u64 b = __hip_atomic_load((const u64*)(p + 4), __ATOMIC_RELAXED, __HIP_MEMORY_SCOPE_AGENT);
  short8 r;
  __builtin_memcpy(&r, &a, 8);
  __builtin_memcpy((char*)&r + 8, &b, 8);
  return r;
}
static __device__ __forceinline__ void st_dev_u16(u16* p, u16 v){
  __hip_atomic_store(p, v, __ATOMIC_RELAXED, __HIP_MEMORY_SCOPE_AGENT);
}

#define SPIN_CAP 1048576u   // hang-breaker: terminate (visibly wrong) vs container kill

// ---------------------------------------------------------------------------
// dtype sniff on h ~ N(0,1); also zeroes barrier flags + generation word.
// ---------------------------------------------------------------------------
__global__ void k_detect(const u32* __restrict__ h32, u32* __restrict__ flag,
                         u32* __restrict__ arr, u32* __restrict__ bar_gen){
  const int lane = threadIdx.x;        // 64
  int cnt = 0;
  for (int i = 0; i < 16; ++i){
    u32 w = h32[lane*16 + i];
    u32 e = (w >> 7) & 0xFFu;
    cnt += (e >= 100u && e <= 140u) ? 1 : 0;
  }
  __hip_atomic_store(arr + lane*32, 0u, __ATOMIC_RELAXED, __HIP_MEMORY_SCOPE_AGENT);
  for (int off = 32; off; off >>= 1) cnt += __shfl_down(cnt, off, 64);
  if (lane == 0){
    flag[0] = (cnt < 512) ? 1u : 0u;   // 1 = fp32 inputs/outputs
    __hip_atomic_store(bar_gen, 0u, __ATOMIC_RELAXED, __HIP_MEMORY_SCOPE_AGENT);
  }
}

// ---------------------------------------------------------------------------
// One-shot W_fc -> bf16 materialization (only needed when inputs are fp32).
// ---------------------------------------------------------------------------
__global__ __launch_bounds__(256) void k_wfc(const void* __restrict__ W_fc,
                                             u16* __restrict__ out,
                                             const u32* __restrict__ flag){
  if (!flag[0]) return;                // bf16 inputs: W_fc used directly
  const long total = (long)V_*H_;
  long i = ((long)blockIdx.x*256 + threadIdx.x)*8;
  const long stride = (long)gridDim.x*256*8;
  for (; i < total; i += stride)
    *(short8*)(out + i) = load8(W_fc, i, 1);
}

// ---------------------------------------------------------------------------
// Phase A: xg[t][q][r][b] (fp32) = emb[tgt[b][t]] . W_ih[g=q*1024+r] + b_ih + b_hh
// ---------------------------------------------------------------------------
__global__ __launch_bounds__(256) void k_xg(
    const int* __restrict__ tgt, const void* __restrict__ emb,
    const void* __restrict__ W_ih, const void* __restrict__ b_ih,
    const void* __restrict__ b_hh, float* __restrict__ xg,
    const u32* __restrict__ flag)
{
  const int is32 = (int)flag[0];
  __shared__ __align__(16) u16 la[64*32];
  __shared__ __align__(16) u16 lb[64*32];
  __shared__ int ids[64];
  const int nb = blockIdx.x;           // gate block   (64)
  const int mb = blockIdx.y;           // token block  (32)
  const int tid = threadIdx.x, lane = tid & 63, wv = tid >> 6;
  const int wm = wv >> 1, wn = wv & 1; // 2x2 wave grid, wave tile 32x32
  const int g0 = nb*64;

  if (tid < 64){
    int m = mb*64 + tid;               // token; t = m>>4, b = m&15; tgt is [B][S]
    ids[tid] = tgt[(m & 15)*S_ + (m >> 4)];
  }
  __syncthreads();

  f32x4 acc[2][2];
#pragma unroll
  for (int i = 0; i < 2; ++i)
#pragma unroll
    for (int j = 0; j < 2; ++j) acc[i][j] = (f32x4){0.f,0.f,0.f,0.f};

  const int srow = tid >> 2, sk = (tid & 3)*8;   // 64 rows x 4 loaders of 8
  const long arow = (long)ids[srow]*E_ + sk;
  const long brow = (long)(g0 + srow)*E_ + sk;

  for (int k0 = 0; k0 < E_; k0 += 32){
    short8 va = load8(emb,  arow + k0, is32);
    short8 vb = load8(W_ih, brow + k0, is32);
    *(short8*)&la[srow*32 + sk] = va;
    *(short8*)&lb[srow*32 + sk] = vb;
    __syncthreads();
    short8 af[2], bfv[2];
#pragma unroll
    for (int mt = 0; mt < 2; ++mt)
      af[mt] = *(const short8*)&la[(wm*32 + mt*16 + (lane & 15))*32 + ((lane >> 4)*8)];
#pragma unroll
    for (int nt = 0; nt < 2; ++nt)
      bfv[nt] = *(const short8*)&lb[(wn*32 + nt*16 + (lane & 15))*32 + ((lane >> 4)*8)];
#pragma unroll
    for (int mt = 0; mt < 2; ++mt)
#pragma unroll
      for (int nt = 0; nt < 2; ++nt)
        acc[mt][nt] = __builtin_amdgcn_mfma_f32_16x16x32_bf16(af[mt], bfv[nt], acc[mt][nt], 0,0,0);
    __syncthreads();
  }

  // epilogue: C rows = token-in-tile (batch within), cols = gate
  const int col = lane & 15, quad = lane >> 4;
#pragma unroll
  for (int nt = 0; nt < 2; ++nt){
    int g = g0 + wn*32 + nt*16 + col;
    float bias = ldf(b_ih, g, is32) + ldf(b_hh, g, is32);
    int q = g >> 10, r = g & 1023;
#pragma unroll
    for (int mt = 0; mt < 2; ++mt){
      int t = mb*4 + wm*2 + mt;
      f32x4 v;
      v[0] = acc[mt][nt][0] + bias;
      v[1] = acc[mt][nt][1] + bias;
      v[2] = acc[mt][nt][2] + bias;
      v[3] = acc[mt][nt][3] + bias;
      *(f32x4*)(xg + ((long)((t*4 + q)*1024 + r)*16 + quad*4)) = v;
    }
  }
}

// ---------------------------------------------------------------------------
// Phase B (persistent, all 128 steps).  Two-hop barrier:
//   arrive   : each WG release-stores arr[s]=gen to its OWN 128B line (parallel)
//   aggregate: ONLY WG0's wave0 gathers the 64 flags (__all), publishes bar_gen
//   wait     : other WGs spin 1-thread-per-WG on the single bar_gen line
// ~127 concurrent pollers vs round-3's 4096 (suspected fabric-starvation hang)
// and vs round-2's 64 serialized fetch_adds (~18k cy/step).  Both spins carry
// a bounded escape: a wedged protocol terminates (visibly wrong) instead of
// killing the container.  h ordering: h stores (write-through) are drained by
// __syncthreads before arrive; release/acquire chain arr->bar_gen is
// transitive, so h is visible at the coherence point before any WG proceeds;
// h loads bypass L1/L2.  Parity X written at t is re-read at t+2 (two barriers
// apart) -- same separation grid.sync() gave.
// ---------------------------------------------------------------------------
__global__ __launch_bounds__(256, 1) void k_steps_all(
    const void* __restrict__ W_hh, const float* __restrict__ xg,
    const void* __restrict__ h_in, const void* __restrict__ c_in,
    u16* __restrict__ h_buf, u16* __restrict__ hs,
    const u32* __restrict__ flag, u32* arr, u32* bar_gen)
{
  const int is32 = (int)flag[0];
  const int s    = blockIdx.x;         // 64
  const int tid  = threadIdx.x;
  const int lane = tid & 63;
  const int wv   = tid >> 6;           // wave -> K slice [wv*256, wv*256+256)

  __shared__ __align__(16) float part[4][4][16][20];  // [wave][gate][r][b pad20]

  // B-operand fragments: rows q*1024 + s*16 + (lane&15), k = wv*256 + quad*8 + j*32
  short8 wf[4][8];
#pragma unroll
  for (int q = 0; q < 4; ++q){
    const long wrow = (long)(q*H_ + s*16 + (lane & 15))*H_ + wv*256 + ((lane >> 4)*8);
#pragma unroll
    for (int j = 0; j < 8; ++j)
      wf[q][j] = load8(W_hh, wrow + j*32, is32);
  }

  // epilogue ownership: thread -> (batch eb, hidden unit s*16+er)
  const int eb = tid >> 4;
  const int er = tid & 15;
  const int co = eb*H_ + s*16 + er;
  float c_val = ldf(c_in, co, is32);   // carry lives in a register

  const int arow = (lane & 15)*H_ + wv*256 + ((lane >> 4)*8);
  const float* xg_b = xg + (s*16 + er)*16 + eb;
  u16* hs_b = hs + (long)eb*S_*H_ + s*16 + er;

  // init parity-0 h (hi + lo residual); each WG initializes exactly its slice
  {
    float hv0 = ldf(h_in, co, is32);
    u16 hi0 = f2bf(hv0);
    st_dev_u16(h_buf + co,         hi0);
    st_dev_u16(h_buf + B_*H_ + co, f2bf(hv0 - bf2f(hi0)));
  }
  __syncthreads();                     // drains vmcnt: h stores at coherence pt
  if (tid == 0)
    __hip_atomic_store(arr + s*32, 1u, __ATOMIC_RELEASE, __HIP_MEMORY_SCOPE_AGENT);

  for (int t = 0; t < S_; ++t){
    // xg prefetch issued BEFORE the wait: latency hides under the spin
    const float* xg_t = xg_b + (long)t*65536;
    float pre0 = xg_t[0], pre1 = xg_t[16384], pre2 = xg_t[32768], pre3 = xg_t[49152];

    const u32 tgen = (u32)(t + 1);
    if (s == 0 && tid < 64){
      // aggregator: wave 0 of WG 0 gathers all 64 per-WG flags
      u32 iters = 0;
      while (true){
        u32 v = __hip_atomic_load(arr + tid*32, __ATOMIC_ACQUIRE, __HIP_MEMORY_SCOPE_AGENT);
        if (__all((int)(v >= tgen))) break;
        if (++iters > SPIN_CAP) break;             // hang-breaker
        __builtin_amdgcn_s_sleep(2);
      }
      if (tid == 0)
        __hip_atomic_store(bar_gen, tgen, __ATOMIC_RELEASE, __HIP_MEMORY_SCOPE_AGENT);
    } else if (tid == 0){
      // waiter: single poller per WG on the single published line
      u32 iters = 0;
      while (__hip_atomic_load(bar_gen, __ATOMIC_ACQUIRE, __HIP_MEMORY_SCOPE_AGENT) < tgen){
        if (++iters > SPIN_CAP) break;             // hang-breaker
        __builtin_amdgcn_s_sleep(2);
      }
    }
    __syncthreads();

    f32x4 acc[4];
#pragma unroll
    for (int q = 0; q < 4; ++q) acc[q] = (f32x4){0.f,0.f,0.f,0.f};
    const u16* hp = h_buf + (t & 1)*(2*B_*H_) + arow;
#pragma unroll
    for (int j = 0; j < 8; ++j){
      short8 ahi = ld_frag_dev(hp + j*32);
      short8 alo = ld_frag_dev(hp + B_*H_ + j*32);
#pragma unroll
      for (int q = 0; q < 4; ++q){
        acc[q] = __builtin_amdgcn_mfma_f32_16x16x32_bf16(ahi, wf[q][j], acc[q], 0,0,0);
        acc[q] = __builtin_amdgcn_mfma_f32_16x16x32_bf16(alo, wf[q][j], acc[q], 0,0,0);
      }
    }
#pragma unroll
    for (int q = 0; q < 4; ++q)
      *(f32x4*)&part[wv][q][lane & 15][(lane >> 4)*4] = acc[q];   // [r][b]
    __syncthreads();

    float p0 = pre0, p1 = pre1, p2 = pre2, p3 = pre3;
#pragma unroll
    for (int w = 0; w < 4; ++w){
      p0 += part[w][0][er][eb];
      p1 += part[w][1][er][eb];
      p2 += part[w][2][er][eb];
      p3 += part[w][3][er][eb];
    }
    float iv = sigm(p0), fv = sigm(p1), gv = tanh_f(p2), ov = sigm(p3);
    c_val = fv*c_val + iv*gv;
    float hv = ov*tanh_f(c_val);
    u16 hi = f2bf(hv);
    u16 lo = f2bf(hv - bf2f(hi));      // residual: h error ~2^-17 instead of 2^-9
    const int po = ((t + 1) & 1)*(2*B_*H_);
    st_dev_u16(h_buf + po + co,         hi);
    st_dev_u16(h_buf + po + B_*H_ + co, lo);

    // arrive(t+2): syncthreads drains everyone's write-through h stores, then
    // one release store per WG to its own line.  hs write off-critical-path.
    __syncthreads();
    if (tid == 0)
      __hip_atomic_store(arr + s*32, (u32)(t + 2), __ATOMIC_RELEASE, __HIP_MEMORY_SCOPE_AGENT);
    hs_b[(long)t*H_] = hi;
  }
}

// ---------------------------------------------------------------------------
// Phase C: logits = hs . W_fc^T + b_fc.  M=2048, N=32000, K=1024.
// Both operands staged bf16 via global_load_lds (W_fc pre-converted when fp32).
// XCD-aware swizzle: the 16 M-tiles sharing one W_fc panel run on ONE XCD.
// ---------------------------------------------------------------------------
__global__ __launch_bounds__(256) void k_logits(
    const u16* __restrict__ hs, const void* __restrict__ W_fc,
    const u16* __restrict__ wcvt, const void* __restrict__ b_fc,
    void* __restrict__ outv, const u32* __restrict__ flag)
{
  const int is32 = (int)flag[0];
  __shared__ __align__(16) u16 la[128*32];
  __shared__ __align__(16) u16 lb[128*32];
  // bijective XCD swizzle over the 4000-block grid (4000 % 8 == 0)
  const int lin  = blockIdx.x;
  const int lin2 = (lin & 7)*500 + (lin >> 3);
  const int mb = lin2 & 15;            // 16 M-tiles (fast: same W_fc panel)
  const int nb = lin2 >> 4;            // 250 N-panels
  const int tid = threadIdx.x, lane = tid & 63, wv = tid >> 6;
  const int wm = wv >> 1, wn = wv & 1; // 2x2 wave grid, wave tile 64x64
  const long m0 = (long)mb*128;
  const long n0 = (long)nb*128;

  const u16* Wb = is32 ? wcvt : (const u16*)W_fc;   // bf16 W_fc (null -> fallback)

  f32x4 acc[4][4];
#pragma unroll
  for (int i = 0; i < 4; ++i)
#pragma unroll
    for (int j = 0; j < 4; ++j) acc[i][j] = (f32x4){0.f,0.f,0.f,0.f};

  const int srow = lane >> 2, scol = (lane & 3)*8;
  const u16* asrc = hs + (m0 + wv*32 + srow)*H_ + scol;
  u16* lda = &la[wv*32*32];
  const u16* bsrc = Wb ? Wb + (n0 + wv*32 + srow)*H_ + scol : (const u16*)0;
  u16* ldb = &lb[wv*32*32];
  const int br = tid >> 2, bk = (tid & 3)*8;     // fallback path: rows br, br+64
  const long brow0 = (long)(n0 + br)*H_ + bk;
  const long brow1 = (long)(n0 + br + 64)*H_ + bk;

  for (int k0 = 0; k0 < H_; k0 += 32){
    gl2lds16(asrc + k0,          lda);
    gl2lds16(asrc + 16*H_ + k0,  lda + 16*32);
    if (Wb){
      gl2lds16(bsrc + k0,          ldb);
      gl2lds16(bsrc + 16*H_ + k0,  ldb + 16*32);
    } else {
      *(short8*)&lb[br*32 + bk]        = load8(W_fc, brow0 + k0, 1);
      *(short8*)&lb[(br + 64)*32 + bk] = load8(W_fc, brow1 + k0, 1);
    }
    __syncthreads();
    short8 af[4], bfr[4];
#pragma unroll
    for (int mt = 0; mt < 4; ++mt)
      af[mt] = *(const short8*)&la[(wm*64 + mt*16 + (lane & 15))*32 + ((lane >> 4)*8)];
#pragma unroll
    for (int nt = 0; nt < 4; ++nt)
      bfr[nt] = *(const short8*)&lb[(wn*64 + nt*16 + (lane & 15))*32 + ((lane >> 4)*8)];
#pragma unroll
    for (int mt = 0; mt < 4; ++mt)
#pragma unroll
      for (int nt = 0; nt < 4; ++nt)
        acc[mt][nt] = __builtin_amdgcn_mfma_f32_16x16x32_bf16(af[mt], bfr[nt], acc[mt][nt], 0,0,0);
    __syncthreads();
  }

  const int col = lane & 15, quad = lane >> 4;
#pragma unroll
  for (int nt = 0; nt < 4; ++nt){
    long n = n0 + wn*64 + nt*16 + col;
    float bias = ldf(b_fc, n, is32);
#pragma unroll
    for (int mt = 0; mt < 4; ++mt){
      long m = m0 + wm*64 + mt*16 + quad*4;
      float v0 = acc[mt][nt][0] + bias;
      float v1 = acc[mt][nt][1] + bias;
      float v2 = acc[mt][nt][2] + bias;
      float v3 = acc[mt][nt][3] + bias;
      if (is32){
        float* p = (float*)outv + m*V_ + n;
        __builtin_nontemporal_store(v0, p);
        __builtin_nontemporal_store(v1, p + V_);
        __builtin_nontemporal_store(v2, p + 2L*V_);
        __builtin_nontemporal_store(v3, p + 3L*V_);
      } else {
        u16* p = (u16*)outv + m*V_ + n;
        __builtin_nontemporal_store(f2bf(v0), p);
        __builtin_nontemporal_store(f2bf(v1), p + V_);
        __builtin_nontemporal_store(f2bf(v2), p + 2L*V_);
        __builtin_nontemporal_store(f2bf(v3), p + 3L*V_);
      }
    }
  }
}

// ---------------------------------------------------------------------------
extern "C" void kernel_launch(void* const* d_in, const int* in_sizes, int n_in,
                              void* d_out, int out_size, void* d_ws, size_t ws_size,
                              hipStream_t stream)
{
  (void)in_sizes; (void)n_in; (void)out_size;
  const int*  tgt  = (const int*)d_in[0];
  const void* h0   = d_in[1];
  const void* c0   = d_in[2];
  const void* emb  = d_in[3];
  const void* W_ih = d_in[4];
  const void* W_hh = d_in[5];
  const void* b_ih = d_in[6];
  const void* b_hh = d_in[7];
  const void* W_fc = d_in[8];
  const void* b_fc = d_in[9];

  // xg (fp32, 33.5 MB) lives in d_out: dead before k_logits overwrites d_out.
  float* xg = (float*)d_out;
  char* ws    = (char*)d_ws;
  u16*   hs      = (u16*)(ws);             // [16][128][1024] bf16  = 4,194,304 B
  u16*   h_buf   = (u16*)(ws + 4194304);   // [2][2][16][1024] bf16 =   131,072 B
  u32*   flag    = (u32*)(ws + 4325376);   // 128B line: 1 = fp32 I/O
  u32*   arr     = (u32*)(ws + 4325504);   // 64 flags x 128B       =     8,192 B
  u32*   bar_gen = (u32*)(ws + 4333696);   // 128B line
  // bf16 W_fc (65,536,000 B) only if workspace allows
  u16*   wcvt  = (ws_size >= (size_t)4334080 + 65536000u) ? (u16*)(ws + 4334080)
                                                          : (u16*)0;

  k_detect<<<1, 64, 0, stream>>>((const u32*)h0, flag, arr, bar_gen);
  dim3 gA(64, 32);
  k_xg<<<gA, 256, 0, stream>>>(tgt, emb, W_ih, b_ih, b_hh, xg, flag);
  if (wcvt)
    k_wfc<<<2048, 256, 0, stream>>>(W_fc, wcvt, flag);

  // Phase B: one cooperative dispatch (co-residency guarantee), two-hop barrier.
  u16* hb  = h_buf;
  u16* hsp = hs;
  void* args[9];
  args[0] = (void*)&W_hh;
  args[1] = (void*)&xg;
  args[2] = (void*)&h0;
  args[3] = (void*)&c0;
  args[4] = (void*)&hb;
  args[5] = (void*)&hsp;
  args[6] = (void*)&flag;
  args[7] = (void*)&arr;
  args[8] = (void*)&bar_gen;
  hipLaunchCooperativeKernel((const void*)k_steps_all, dim3(64), dim3(256),
                             args, 0, stream);

  dim3 gC(4000);
  k_logits<<<gC, 256, 0, stream>>>(hs, W_fc, wcvt, b_fc, d_out, flag);
}

// Round 5
// 1367.036 us; speedup vs baseline: 2.2505x; 1.2370x over previous
//
#include <hip/hip_runtime.h>

typedef unsigned short u16;
typedef unsigned int   u32;
typedef unsigned long long u64;
typedef __attribute__((ext_vector_type(8))) short short8;  // 8 bf16 (4 VGPRs) MFMA frag
typedef __attribute__((ext_vector_type(4))) float f32x4;   // MFMA 16x16 accumulator

#define B_   16
#define S_   128
#define H_   1024
#define E_   512
#define V_   32000

static __device__ __forceinline__ float bf2f(u16 x){
  u32 u = ((u32)x) << 16; float f; __builtin_memcpy(&f, &u, 4); return f;
}
static __device__ __forceinline__ u16 f2bf(float f){
  u32 u; __builtin_memcpy(&u, &f, 4);
  u += 0x7fffu + ((u >> 16) & 1u);           // round-to-nearest-even
  return (u16)(u >> 16);
}
static __device__ __forceinline__ void gl2lds16(const void* g, void* l){
  // async global->LDS, 16B/lane; LDS dest = wave-uniform base + lane*16
  __builtin_amdgcn_global_load_lds((const __attribute__((address_space(1))) u32*)g,
                                   (__attribute__((address_space(3))) u32*)l, 16, 0, 0);
}
static __device__ __forceinline__ float sigm(float x){ return 1.0f/(1.0f + __expf(-x)); }
static __device__ __forceinline__ float tanh_f(float x){
  float a = fabsf(x);
  float e = __expf(-2.0f*a);
  float r = (1.0f - e)/(1.0f + e);           // e<=1 always: no inf/NaN
  return x < 0.0f ? -r : r;
}
// dtype-agnostic scalar load (element index i)
static __device__ __forceinline__ float ldf(const void* base, long i, int is32){
  return is32 ? ((const float*)base)[i] : bf2f(((const u16*)base)[i]);
}
// dtype-agnostic 8-element load -> packed bf16 (i must be 8-aligned)
static __device__ __forceinline__ short8 load8(const void* base, long i, int is32){
  short8 r;
  if (is32){
    const float* p = (const float*)base + i;
    f32x4 a = *(const f32x4*)p;
    f32x4 b = *(const f32x4*)(p + 4);
    r[0]=(short)f2bf(a[0]); r[1]=(short)f2bf(a[1]);
    r[2]=(short)f2bf(a[2]); r[3]=(short)f2bf(a[3]);
    r[4]=(short)f2bf(b[0]); r[5]=(short)f2bf(b[1]);
    r[6]=(short)f2bf(b[2]); r[7]=(short)f2bf(b[3]);
  } else {
    r = *(const short8*)((const u16*)base + i);
  }
  return r;
}

// device-coherent bypass accessors for the h ping-pong buffer.  RELAXED agent
// atomics = plain sc0/sc1 loads/stores (no buffer_inv / buffer_wbl2): loads
// are served at the coherence point, stores write through to it.  Correctness
// of relaxed-only h exchange is established (rounds 2/4 verified with it).
static __device__ __forceinline__ short8 ld_frag_dev(const u16* p){
  u64 a = __hip_atomic_load((const u64*)p,       __ATOMIC_RELAXED, __HIP_MEMORY_SCOPE_AGENT);
  u64 b = __hip_atomic_load((const u64*)(p + 4), __ATOMIC_RELAXED, __HIP_MEMORY_SCOPE_AGENT);
  short8 r;
  __builtin_memcpy(&r, &a, 8);
  __builtin_memcpy((char*)&r + 8, &b, 8);
  return r;
}
static __device__ __forceinline__ void st_dev_u16(u16* p, u16 v){
  __hip_atomic_store(p, v, __ATOMIC_RELAXED, __HIP_MEMORY_SCOPE_AGENT);
}

#define SPIN_CAP 1048576u   // hang-breaker: terminate (visibly wrong) vs container kill

// ---------------------------------------------------------------------------
// dtype sniff on h ~ N(0,1); also zeroes barrier flags + generation word.
// ---------------------------------------------------------------------------
__global__ void k_detect(const u32* __restrict__ h32, u32* __restrict__ flag,
                         u32* __restrict__ arr, u32* __restrict__ bar_gen){
  const int lane = threadIdx.x;        // 64
  int cnt = 0;
  for (int i = 0; i < 16; ++i){
    u32 w = h32[lane*16 + i];
    u32 e = (w >> 7) & 0xFFu;
    cnt += (e >= 100u && e <= 140u) ? 1 : 0;
  }
  __hip_atomic_store(arr + lane*32, 0u, __ATOMIC_RELAXED, __HIP_MEMORY_SCOPE_AGENT);
  for (int off = 32; off; off >>= 1) cnt += __shfl_down(cnt, off, 64);
  if (lane == 0){
    flag[0] = (cnt < 512) ? 1u : 0u;   // 1 = fp32 inputs/outputs
    __hip_atomic_store(bar_gen, 0u, __ATOMIC_RELAXED, __HIP_MEMORY_SCOPE_AGENT);
  }
}

// ---------------------------------------------------------------------------
// One-shot W_fc -> bf16 materialization (only needed when inputs are fp32).
// ---------------------------------------------------------------------------
__global__ __launch_bounds__(256) void k_wfc(const void* __restrict__ W_fc,
                                             u16* __restrict__ out,
                                             const u32* __restrict__ flag){
  if (!flag[0]) return;                // bf16 inputs: W_fc used directly
  const long total = (long)V_*H_;
  long i = ((long)blockIdx.x*256 + threadIdx.x)*8;
  const long stride = (long)gridDim.x*256*8;
  for (; i < total; i += stride)
    *(short8*)(out + i) = load8(W_fc, i, 1);
}

// ---------------------------------------------------------------------------
// Phase A: xg[t][q][r][b] (fp32) = emb[tgt[b][t]] . W_ih[g=q*1024+r] + b_ih + b_hh
// ---------------------------------------------------------------------------
__global__ __launch_bounds__(256) void k_xg(
    const int* __restrict__ tgt, const void* __restrict__ emb,
    const void* __restrict__ W_ih, const void* __restrict__ b_ih,
    const void* __restrict__ b_hh, float* __restrict__ xg,
    const u32* __restrict__ flag)
{
  const int is32 = (int)flag[0];
  __shared__ __align__(16) u16 la[64*32];
  __shared__ __align__(16) u16 lb[64*32];
  __shared__ int ids[64];
  const int nb = blockIdx.x;           // gate block   (64)
  const int mb = blockIdx.y;           // token block  (32)
  const int tid = threadIdx.x, lane = tid & 63, wv = tid >> 6;
  const int wm = wv >> 1, wn = wv & 1; // 2x2 wave grid, wave tile 32x32
  const int g0 = nb*64;

  if (tid < 64){
    int m = mb*64 + tid;               // token; t = m>>4, b = m&15; tgt is [B][S]
    ids[tid] = tgt[(m & 15)*S_ + (m >> 4)];
  }
  __syncthreads();

  f32x4 acc[2][2];
#pragma unroll
  for (int i = 0; i < 2; ++i)
#pragma unroll
    for (int j = 0; j < 2; ++j) acc[i][j] = (f32x4){0.f,0.f,0.f,0.f};

  const int srow = tid >> 2, sk = (tid & 3)*8;   // 64 rows x 4 loaders of 8
  const long arow = (long)ids[srow]*E_ + sk;
  const long brow = (long)(g0 + srow)*E_ + sk;

  for (int k0 = 0; k0 < E_; k0 += 32){
    short8 va = load8(emb,  arow + k0, is32);
    short8 vb = load8(W_ih, brow + k0, is32);
    *(short8*)&la[srow*32 + sk] = va;
    *(short8*)&lb[srow*32 + sk] = vb;
    __syncthreads();
    short8 af[2], bfv[2];
#pragma unroll
    for (int mt = 0; mt < 2; ++mt)
      af[mt] = *(const short8*)&la[(wm*32 + mt*16 + (lane & 15))*32 + ((lane >> 4)*8)];
#pragma unroll
    for (int nt = 0; nt < 2; ++nt)
      bfv[nt] = *(const short8*)&lb[(wn*32 + nt*16 + (lane & 15))*32 + ((lane >> 4)*8)];
#pragma unroll
    for (int mt = 0; mt < 2; ++mt)
#pragma unroll
      for (int nt = 0; nt < 2; ++nt)
        acc[mt][nt] = __builtin_amdgcn_mfma_f32_16x16x32_bf16(af[mt], bfv[nt], acc[mt][nt], 0,0,0);
    __syncthreads();
  }

  // epilogue: C rows = token-in-tile (batch within), cols = gate
  const int col = lane & 15, quad = lane >> 4;
#pragma unroll
  for (int nt = 0; nt < 2; ++nt){
    int g = g0 + wn*32 + nt*16 + col;
    float bias = ldf(b_ih, g, is32) + ldf(b_hh, g, is32);
    int q = g >> 10, r = g & 1023;
#pragma unroll
    for (int mt = 0; mt < 2; ++mt){
      int t = mb*4 + wm*2 + mt;
      f32x4 v;
      v[0] = acc[mt][nt][0] + bias;
      v[1] = acc[mt][nt][1] + bias;
      v[2] = acc[mt][nt][2] + bias;
      v[3] = acc[mt][nt][3] + bias;
      *(f32x4*)(xg + ((long)((t*4 + q)*1024 + r)*16 + quad*4)) = v;
    }
  }
}

// ---------------------------------------------------------------------------
// Phase B (persistent, all 128 steps).  Two-hop barrier, ALL-RELAXED atomics:
// acquire/release agent atomics emit buffer_inv / buffer_wbl2 (L1/L2
// invalidate + dirty-L2 writeback) -- executed per poll iteration / per step
// they reproduce most of grid.sync()'s cost, which is why rounds 2 and 4
// measured the same 8.4us/step.  All cross-WG data (h ping-pong) is accessed
// via RELAXED bypassing atomics (served at the coherence point), so no cache
// maintenance is needed at all; the only ordering requirement is that the
// arrive store issues after the h stores complete, which the vmcnt(0) drain
// inside __syncthreads provides.  h fragments are batch-loaded into registers
// before the MFMA loop (one latency instead of 8 dependent round-trips).
// ---------------------------------------------------------------------------
__global__ __launch_bounds__(256, 1) void k_steps_all(
    const void* __restrict__ W_hh, const float* __restrict__ xg,
    const void* __restrict__ h_in, const void* __restrict__ c_in,
    u16* __restrict__ h_buf, u16* __restrict__ hs,
    const u32* __restrict__ flag, u32* arr, u32* bar_gen)
{
  const int is32 = (int)flag[0];
  const int s    = blockIdx.x;         // 64
  const int tid  = threadIdx.x;
  const int lane = tid & 63;
  const int wv   = tid >> 6;           // wave -> K slice [wv*256, wv*256+256)

  __shared__ __align__(16) float part[4][4][16][20];  // [wave][gate][r][b pad20]

  // B-operand fragments: rows q*1024 + s*16 + (lane&15), k = wv*256 + quad*8 + j*32
  short8 wf[4][8];
#pragma unroll
  for (int q = 0; q < 4; ++q){
    const long wrow = (long)(q*H_ + s*16 + (lane & 15))*H_ + wv*256 + ((lane >> 4)*8);
#pragma unroll
    for (int j = 0; j < 8; ++j)
      wf[q][j] = load8(W_hh, wrow + j*32, is32);
  }

  // epilogue ownership: thread -> (batch eb, hidden unit s*16+er)
  const int eb = tid >> 4;
  const int er = tid & 15;
  const int co = eb*H_ + s*16 + er;
  float c_val = ldf(c_in, co, is32);   // carry lives in a register

  const int arow = (lane & 15)*H_ + wv*256 + ((lane >> 4)*8);
  const float* xg_b = xg + (s*16 + er)*16 + eb;
  u16* hs_b = hs + (long)eb*S_*H_ + s*16 + er;

  // init parity-0 h (hi + lo residual); each WG initializes exactly its slice
  {
    float hv0 = ldf(h_in, co, is32);
    u16 hi0 = f2bf(hv0);
    st_dev_u16(h_buf + co,         hi0);
    st_dev_u16(h_buf + B_*H_ + co, f2bf(hv0 - bf2f(hi0)));
  }
  __syncthreads();                     // vmcnt(0) drain: h at coherence point
  if (tid == 0)
    __hip_atomic_store(arr + s*32, 1u, __ATOMIC_RELAXED, __HIP_MEMORY_SCOPE_AGENT);

  for (int t = 0; t < S_; ++t){
    // xg prefetch issued BEFORE the wait: latency hides under the spin
    const float* xg_t = xg_b + (long)t*65536;
    float pre0 = xg_t[0], pre1 = xg_t[16384], pre2 = xg_t[32768], pre3 = xg_t[49152];

    const u32 tgen = (u32)(t + 1);
    if (s == 0 && tid < 64){
      // aggregator: wave 0 of WG 0 gathers all 64 per-WG flags (relaxed polls)
      u32 iters = 0;
      while (true){
        u32 v = __hip_atomic_load(arr + tid*32, __ATOMIC_RELAXED, __HIP_MEMORY_SCOPE_AGENT);
        if (__all((int)(v >= tgen))) break;
        if (++iters > SPIN_CAP) break;             // hang-breaker
        __builtin_amdgcn_s_sleep(1);
      }
      if (tid == 0)
        __hip_atomic_store(bar_gen, tgen, __ATOMIC_RELAXED, __HIP_MEMORY_SCOPE_AGENT);
    } else if (tid == 0){
      // waiter: single relaxed poller per WG on the single published line
      u32 iters = 0;
      while (__hip_atomic_load(bar_gen, __ATOMIC_RELAXED, __HIP_MEMORY_SCOPE_AGENT) < tgen){
        if (++iters > SPIN_CAP) break;             // hang-breaker
        __builtin_amdgcn_s_sleep(1);
      }
    }
    __syncthreads();

    // batch-load ALL h fragments first: 32 independent bypass loads in flight
    // at once (vs 8 dependent load->MFMA round-trips).
    const u16* hp = h_buf + (t & 1)*(2*B_*H_) + arow;
    short8 ahi[8], alo[8];
#pragma unroll
    for (int j = 0; j < 8; ++j){
      ahi[j] = ld_frag_dev(hp + j*32);
      alo[j] = ld_frag_dev(hp + B_*H_ + j*32);
    }

    f32x4 acc[4];
#pragma unroll
    for (int q = 0; q < 4; ++q) acc[q] = (f32x4){0.f,0.f,0.f,0.f};
#pragma unroll
    for (int j = 0; j < 8; ++j){
#pragma unroll
      for (int q = 0; q < 4; ++q){
        acc[q] = __builtin_amdgcn_mfma_f32_16x16x32_bf16(ahi[j], wf[q][j], acc[q], 0,0,0);
        acc[q] = __builtin_amdgcn_mfma_f32_16x16x32_bf16(alo[j], wf[q][j], acc[q], 0,0,0);
      }
    }
#pragma unroll
    for (int q = 0; q < 4; ++q)
      *(f32x4*)&part[wv][q][lane & 15][(lane >> 4)*4] = acc[q];   // [r][b]
    __syncthreads();

    float p0 = pre0, p1 = pre1, p2 = pre2, p3 = pre3;
#pragma unroll
    for (int w = 0; w < 4; ++w){
      p0 += part[w][0][er][eb];
      p1 += part[w][1][er][eb];
      p2 += part[w][2][er][eb];
      p3 += part[w][3][er][eb];
    }
    float iv = sigm(p0), fv = sigm(p1), gv = tanh_f(p2), ov = sigm(p3);
    c_val = fv*c_val + iv*gv;
    float hv = ov*tanh_f(c_val);
    u16 hi = f2bf(hv);
    u16 lo = f2bf(hv - bf2f(hi));      // residual: h error ~2^-17 instead of 2^-9
    const int po = ((t + 1) & 1)*(2*B_*H_);
    st_dev_u16(h_buf + po + co,         hi);
    st_dev_u16(h_buf + po + B_*H_ + co, lo);

    // arrive(t+2): __syncthreads drains every thread's write-through h stores
    // (vmcnt(0) before s_barrier), then one relaxed store per WG to its own
    // line.  Parity X written at t is re-read at t+2 -- two barriers apart.
    __syncthreads();
    if (tid == 0)
      __hip_atomic_store(arr + s*32, (u32)(t + 2), __ATOMIC_RELAXED, __HIP_MEMORY_SCOPE_AGENT);
    hs_b[(long)t*H_] = hi;
  }
}

// ---------------------------------------------------------------------------
// Phase C: logits = hs . W_fc^T + b_fc.  M=2048, N=32000, K=1024.
// Both operands staged bf16 via global_load_lds (W_fc pre-converted when fp32).
// XCD-aware swizzle: the 16 M-tiles sharing one W_fc panel run on ONE XCD.
// ---------------------------------------------------------------------------
__global__ __launch_bounds__(256) void k_logits(
    const u16* __restrict__ hs, const void* __restrict__ W_fc,
    const u16* __restrict__ wcvt, const void* __restrict__ b_fc,
    void* __restrict__ outv, const u32* __restrict__ flag)
{
  const int is32 = (int)flag[0];
  __shared__ __align__(16) u16 la[128*32];
  __shared__ __align__(16) u16 lb[128*32];
  // bijective XCD swizzle over the 4000-block grid (4000 % 8 == 0)
  const int lin  = blockIdx.x;
  const int lin2 = (lin & 7)*500 + (lin >> 3);
  const int mb = lin2 & 15;            // 16 M-tiles (fast: same W_fc panel)
  const int nb = lin2 >> 4;            // 250 N-panels
  const int tid = threadIdx.x, lane = tid & 63, wv = tid >> 6;
  const int wm = wv >> 1, wn = wv & 1; // 2x2 wave grid, wave tile 64x64
  const long m0 = (long)mb*128;
  const long n0 = (long)nb*128;

  const u16* Wb = is32 ? wcvt : (const u16*)W_fc;   // bf16 W_fc (null -> fallback)

  f32x4 acc[4][4];
#pragma unroll
  for (int i = 0; i < 4; ++i)
#pragma unroll
    for (int j = 0; j < 4; ++j) acc[i][j] = (f32x4){0.f,0.f,0.f,0.f};

  const int srow = lane >> 2, scol = (lane & 3)*8;
  const u16* asrc = hs + (m0 + wv*32 + srow)*H_ + scol;
  u16* lda = &la[wv*32*32];
  const u16* bsrc = Wb ? Wb + (n0 + wv*32 + srow)*H_ + scol : (const u16*)0;
  u16* ldb = &lb[wv*32*32];
  const int br = tid >> 2, bk = (tid & 3)*8;     // fallback path: rows br, br+64
  const long brow0 = (long)(n0 + br)*H_ + bk;
  const long brow1 = (long)(n0 + br + 64)*H_ + bk;

  for (int k0 = 0; k0 < H_; k0 += 32){
    gl2lds16(asrc + k0,          lda);
    gl2lds16(asrc + 16*H_ + k0,  lda + 16*32);
    if (Wb){
      gl2lds16(bsrc + k0,          ldb);
      gl2lds16(bsrc + 16*H_ + k0,  ldb + 16*32);
    } else {
      *(short8*)&lb[br*32 + bk]        = load8(W_fc, brow0 + k0, 1);
      *(short8*)&lb[(br + 64)*32 + bk] = load8(W_fc, brow1 + k0, 1);
    }
    __syncthreads();
    short8 af[4], bfr[4];
#pragma unroll
    for (int mt = 0; mt < 4; ++mt)
      af[mt] = *(const short8*)&la[(wm*64 + mt*16 + (lane & 15))*32 + ((lane >> 4)*8)];
#pragma unroll
    for (int nt = 0; nt < 4; ++nt)
      bfr[nt] = *(const short8*)&lb[(wn*64 + nt*16 + (lane & 15))*32 + ((lane >> 4)*8)];
#pragma unroll
    for (int mt = 0; mt < 4; ++mt)
#pragma unroll
      for (int nt = 0; nt < 4; ++nt)
        acc[mt][nt] = __builtin_amdgcn_mfma_f32_16x16x32_bf16(af[mt], bfr[nt], acc[mt][nt], 0,0,0);
    __syncthreads();
  }

  const int col = lane & 15, quad = lane >> 4;
#pragma unroll
  for (int nt = 0; nt < 4; ++nt){
    long n = n0 + wn*64 + nt*16 + col;
    float bias = ldf(b_fc, n, is32);
#pragma unroll
    for (int mt = 0; mt < 4; ++mt){
      long m = m0 + wm*64 + mt*16 + quad*4;
      float v0 = acc[mt][nt][0] + bias;
      float v1 = acc[mt][nt][1] + bias;
      float v2 = acc[mt][nt][2] + bias;
      float v3 = acc[mt][nt][3] + bias;
      if (is32){
        float* p = (float*)outv + m*V_ + n;
        __builtin_nontemporal_store(v0, p);
        __builtin_nontemporal_store(v1, p + V_);
        __builtin_nontemporal_store(v2, p + 2L*V_);
        __builtin_nontemporal_store(v3, p + 3L*V_);
      } else {
        u16* p = (u16*)outv + m*V_ + n;
        __builtin_nontemporal_store(f2bf(v0), p);
        __builtin_nontemporal_store(f2bf(v1), p + V_);
        __builtin_nontemporal_store(f2bf(v2), p + 2L*V_);
        __builtin_nontemporal_store(f2bf(v3), p + 3L*V_);
      }
    }
  }
}

// ---------------------------------------------------------------------------
extern "C" void kernel_launch(void* const* d_in, const int* in_sizes, int n_in,
                              void* d_out, int out_size, void* d_ws, size_t ws_size,
                              hipStream_t stream)
{
  (void)in_sizes; (void)n_in; (void)out_size;
  const int*  tgt  = (const int*)d_in[0];
  const void* h0   = d_in[1];
  const void* c0   = d_in[2];
  const void* emb  = d_in[3];
  const void* W_ih = d_in[4];
  const void* W_hh = d_in[5];
  const void* b_ih = d_in[6];
  const void* b_hh = d_in[7];
  const void* W_fc = d_in[8];
  const void* b_fc = d_in[9];

  // xg (fp32, 33.5 MB) lives in d_out: dead before k_logits overwrites d_out.
  float* xg = (float*)d_out;
  char* ws    = (char*)d_ws;
  u16*   hs      = (u16*)(ws);             // [16][128][1024] bf16  = 4,194,304 B
  u16*   h_buf   = (u16*)(ws + 4194304);   // [2][2][16][1024] bf16 =   131,072 B
  u32*   flag    = (u32*)(ws + 4325376);   // 128B line: 1 = fp32 I/O
  u32*   arr     = (u32*)(ws + 4325504);   // 64 flags x 128B       =     8,192 B
  u32*   bar_gen = (u32*)(ws + 4333696);   // 128B line
  // bf16 W_fc (65,536,000 B) only if workspace allows
  u16*   wcvt  = (ws_size >= (size_t)4334080 + 65536000u) ? (u16*)(ws + 4334080)
                                                          : (u16*)0;

  k_detect<<<1, 64, 0, stream>>>((const u32*)h0, flag, arr, bar_gen);
  dim3 gA(64, 32);
  k_xg<<<gA, 256, 0, stream>>>(tgt, emb, W_ih, b_ih, b_hh, xg, flag);
  if (wcvt)
    k_wfc<<<2048, 256, 0, stream>>>(W_fc, wcvt, flag);

  // Phase B: one cooperative dispatch (co-residency guarantee), relaxed barrier.
  u16* hb  = h_buf;
  u16* hsp = hs;
  void* args[9];
  args[0] = (void*)&W_hh;
  args[1] = (void*)&xg;
  args[2] = (void*)&h0;
  args[3] = (void*)&c0;
  args[4] = (void*)&hb;
  args[5] = (void*)&hsp;
  args[6] = (void*)&flag;
  args[7] = (void*)&arr;
  args[8] = (void*)&bar_gen;
  hipLaunchCooperativeKernel((const void*)k_steps_all, dim3(64), dim3(256),
                             args, 0, stream);

  dim3 gC(4000);
  k_logits<<<gC, 256, 0, stream>>>(hs, W_fc, wcvt, b_fc, d_out, flag);
}

// Round 6
// 1216.497 us; speedup vs baseline: 2.5290x; 1.1237x over previous
//
#include <hip/hip_runtime.h>

typedef unsigned short u16;
typedef unsigned int   u32;
typedef unsigned long long u64;
typedef __attribute__((ext_vector_type(8))) short short8;  // 8 bf16 (4 VGPRs) MFMA frag
typedef __attribute__((ext_vector_type(4))) float f32x4;   // MFMA 16x16 accumulator

#define B_   16
#define S_   128
#define H_   1024
#define E_   512
#define V_   32000

static __device__ __forceinline__ float bf2f(u16 x){
  u32 u = ((u32)x) << 16; float f; __builtin_memcpy(&f, &u, 4); return f;
}
static __device__ __forceinline__ u16 f2bf(float f){
  u32 u; __builtin_memcpy(&u, &f, 4);
  u += 0x7fffu + ((u >> 16) & 1u);           // round-to-nearest-even
  return (u16)(u >> 16);
}
static __device__ __forceinline__ void gl2lds16(const void* g, void* l){
  // async global->LDS, 16B/lane; LDS dest = wave-uniform base + lane*16
  __builtin_amdgcn_global_load_lds((const __attribute__((address_space(1))) u32*)g,
                                   (__attribute__((address_space(3))) u32*)l, 16, 0, 0);
}
static __device__ __forceinline__ float sigm(float x){ return 1.0f/(1.0f + __expf(-x)); }
static __device__ __forceinline__ float tanh_f(float x){
  float a = fabsf(x);
  float e = __expf(-2.0f*a);
  float r = (1.0f - e)/(1.0f + e);           // e<=1 always: no inf/NaN
  return x < 0.0f ? -r : r;
}
// dtype-agnostic scalar load (element index i)
static __device__ __forceinline__ float ldf(const void* base, long i, int is32){
  return is32 ? ((const float*)base)[i] : bf2f(((const u16*)base)[i]);
}
// dtype-agnostic 8-element load -> packed bf16 (i must be 8-aligned)
static __device__ __forceinline__ short8 load8(const void* base, long i, int is32){
  short8 r;
  if (is32){
    const float* p = (const float*)base + i;
    f32x4 a = *(const f32x4*)p;
    f32x4 b = *(const f32x4*)(p + 4);
    r[0]=(short)f2bf(a[0]); r[1]=(short)f2bf(a[1]);
    r[2]=(short)f2bf(a[2]); r[3]=(short)f2bf(a[3]);
    r[4]=(short)f2bf(b[0]); r[5]=(short)f2bf(b[1]);
    r[6]=(short)f2bf(b[2]); r[7]=(short)f2bf(b[3]);
  } else {
    r = *(const short8*)((const u16*)base + i);
  }
  return r;
}

// device-coherent bypass accessors (RELAXED agent atomics: plain sc0/sc1 ops,
// no buffer_inv/buffer_wbl2 -- served at the coherence point).
static __device__ __forceinline__ short8 ld_frag_dev(const u16* p){
  u64 a = __hip_atomic_load((const u64*)p,       __ATOMIC_RELAXED, __HIP_MEMORY_SCOPE_AGENT);
  u64 b = __hip_atomic_load((const u64*)(p + 4), __ATOMIC_RELAXED, __HIP_MEMORY_SCOPE_AGENT);
  short8 r;
  __builtin_memcpy(&r, &a, 8);
  __builtin_memcpy((char*)&r + 8, &b, 8);
  return r;
}
static __device__ __forceinline__ void st_dev_u16(u16* p, u16 v){
  __hip_atomic_store(p, v, __ATOMIC_RELAXED, __HIP_MEMORY_SCOPE_AGENT);
}
static __device__ __forceinline__ u32 ld_dev_u32(const u32* p){
  return __hip_atomic_load(p, __ATOMIC_RELAXED, __HIP_MEMORY_SCOPE_AGENT);
}
static __device__ __forceinline__ void st_dev_u32(u32* p, u32 v){
  __hip_atomic_store(p, v, __ATOMIC_RELAXED, __HIP_MEMORY_SCOPE_AGENT);
}

#define SPIN_CAP 1048576u   // hang-breaker: terminate (visibly wrong) vs container kill

// ---------------------------------------------------------------------------
// dtype sniff on h ~ N(0,1); zeroes barrier flags, generation, progress, ticket.
// ---------------------------------------------------------------------------
__global__ void k_detect(const u32* __restrict__ h32, u32* __restrict__ flag,
                         u32* __restrict__ arr, u32* __restrict__ bar_gen,
                         u32* __restrict__ prog, u32* __restrict__ ticket){
  const int lane = threadIdx.x;        // 64
  int cnt = 0;
  for (int i = 0; i < 16; ++i){
    u32 w = h32[lane*16 + i];
    u32 e = (w >> 7) & 0xFFu;
    cnt += (e >= 100u && e <= 140u) ? 1 : 0;
  }
  st_dev_u32(arr + lane*32, 0u);
  for (int off = 32; off; off >>= 1) cnt += __shfl_down(cnt, off, 64);
  if (lane == 0){
    flag[0] = (cnt < 512) ? 1u : 0u;   // 1 = fp32 inputs/outputs
    st_dev_u32(bar_gen, 0u);
    st_dev_u32(prog, 0u);
    st_dev_u32(ticket, 0u);
  }
}

// ---------------------------------------------------------------------------
// One-shot W_fc -> bf16 materialization (only needed when inputs are fp32).
// ---------------------------------------------------------------------------
__global__ __launch_bounds__(256) void k_wfc(const void* __restrict__ W_fc,
                                             u16* __restrict__ out,
                                             const u32* __restrict__ flag){
  if (!flag[0]) return;                // bf16 inputs: W_fc used directly
  const long total = (long)V_*H_;
  long i = ((long)blockIdx.x*256 + threadIdx.x)*8;
  const long stride = (long)gridDim.x*256*8;
  for (; i < total; i += stride)
    *(short8*)(out + i) = load8(W_fc, i, 1);
}

// ---------------------------------------------------------------------------
// Phase A: xg[t][q][r][b] (fp32) = emb[tgt[b][t]] . W_ih[g=q*1024+r] + b_ih + b_hh
// ---------------------------------------------------------------------------
__global__ __launch_bounds__(256) void k_xg(
    const int* __restrict__ tgt, const void* __restrict__ emb,
    const void* __restrict__ W_ih, const void* __restrict__ b_ih,
    const void* __restrict__ b_hh, float* __restrict__ xg,
    const u32* __restrict__ flag)
{
  const int is32 = (int)flag[0];
  __shared__ __align__(16) u16 la[64*32];
  __shared__ __align__(16) u16 lb[64*32];
  __shared__ int ids[64];
  const int nb = blockIdx.x;           // gate block   (64)
  const int mb = blockIdx.y;           // token block  (32)
  const int tid = threadIdx.x, lane = tid & 63, wv = tid >> 6;
  const int wm = wv >> 1, wn = wv & 1; // 2x2 wave grid, wave tile 32x32
  const int g0 = nb*64;

  if (tid < 64){
    int m = mb*64 + tid;               // token; t = m>>4, b = m&15; tgt is [B][S]
    ids[tid] = tgt[(m & 15)*S_ + (m >> 4)];
  }
  __syncthreads();

  f32x4 acc[2][2];
#pragma unroll
  for (int i = 0; i < 2; ++i)
#pragma unroll
    for (int j = 0; j < 2; ++j) acc[i][j] = (f32x4){0.f,0.f,0.f,0.f};

  const int srow = tid >> 2, sk = (tid & 3)*8;   // 64 rows x 4 loaders of 8
  const long arow = (long)ids[srow]*E_ + sk;
  const long brow = (long)(g0 + srow)*E_ + sk;

  for (int k0 = 0; k0 < E_; k0 += 32){
    short8 va = load8(emb,  arow + k0, is32);
    short8 vb = load8(W_ih, brow + k0, is32);
    *(short8*)&la[srow*32 + sk] = va;
    *(short8*)&lb[srow*32 + sk] = vb;
    __syncthreads();
    short8 af[2], bfv[2];
#pragma unroll
    for (int mt = 0; mt < 2; ++mt)
      af[mt] = *(const short8*)&la[(wm*32 + mt*16 + (lane & 15))*32 + ((lane >> 4)*8)];
#pragma unroll
    for (int nt = 0; nt < 2; ++nt)
      bfv[nt] = *(const short8*)&lb[(wn*32 + nt*16 + (lane & 15))*32 + ((lane >> 4)*8)];
#pragma unroll
    for (int mt = 0; mt < 2; ++mt)
#pragma unroll
      for (int nt = 0; nt < 2; ++nt)
        acc[mt][nt] = __builtin_amdgcn_mfma_f32_16x16x32_bf16(af[mt], bfv[nt], acc[mt][nt], 0,0,0);
    __syncthreads();
  }

  const int col = lane & 15, quad = lane >> 4;
#pragma unroll
  for (int nt = 0; nt < 2; ++nt){
    int g = g0 + wn*32 + nt*16 + col;
    float bias = ldf(b_ih, g, is32) + ldf(b_hh, g, is32);
    int q = g >> 10, r = g & 1023;
#pragma unroll
    for (int mt = 0; mt < 2; ++mt){
      int t = mb*4 + wm*2 + mt;
      f32x4 v;
      v[0] = acc[mt][nt][0] + bias;
      v[1] = acc[mt][nt][1] + bias;
      v[2] = acc[mt][nt][2] + bias;
      v[3] = acc[mt][nt][3] + bias;
      *(f32x4*)(xg + ((long)((t*4 + q)*1024 + r)*16 + quad*4)) = v;
    }
  }
}

// ---------------------------------------------------------------------------
// Shared consumer tile body: logits tile (jt, np).
// M-tile rows r (0..127) -> hs row (r>>3)*128 + jt*8 + (r&7): 8 timesteps x
// all 16 batches, so the tile is READY after step jt*8+7.
// ---------------------------------------------------------------------------
static __device__ __forceinline__ void logits_tile(
    const u16* __restrict__ hs, const u16* Wb, const void* __restrict__ W_fc,
    const void* __restrict__ b_fc, void* __restrict__ outv,
    int is32, int jt, int np, int tid, u16* la, u16* lb)
{
  const int lane = tid & 63, wv = tid >> 6;
  const int wm = wv >> 1, wn = wv & 1; // 2x2 wave grid, wave tile 64x64
  const long n0 = (long)np*128;

  f32x4 acc[4][4];
#pragma unroll
  for (int i = 0; i < 4; ++i)
#pragma unroll
    for (int j = 0; j < 4; ++j) acc[i][j] = (f32x4){0.f,0.f,0.f,0.f};

  const int srow = lane >> 2, scol = (lane & 3)*8;
  const int r0 = wv*32 + srow, r1 = r0 + 16;
  const long arow0 = ((long)(r0 >> 3)*S_ + jt*8 + (r0 & 7))*H_ + scol;
  const long arow1 = ((long)(r1 >> 3)*S_ + jt*8 + (r1 & 7))*H_ + scol;
  u16* lda = &la[wv*32*32];
  const u16* bsrc = Wb ? Wb + (n0 + wv*32 + srow)*H_ + scol : (const u16*)0;
  u16* ldb = &lb[wv*32*32];
  const int br = tid >> 2, bk = (tid & 3)*8;     // fallback path: rows br, br+64
  const long brow0 = (long)(n0 + br)*H_ + bk;
  const long brow1 = (long)(n0 + br + 64)*H_ + bk;

  for (int k0 = 0; k0 < H_; k0 += 32){
    gl2lds16(hs + arow0 + k0, lda);
    gl2lds16(hs + arow1 + k0, lda + 16*32);
    if (Wb){
      gl2lds16(bsrc + k0,         ldb);
      gl2lds16(bsrc + 16*H_ + k0, ldb + 16*32);
    } else {
      *(short8*)&lb[br*32 + bk]        = load8(W_fc, brow0 + k0, 1);
      *(short8*)&lb[(br + 64)*32 + bk] = load8(W_fc, brow1 + k0, 1);
    }
    __syncthreads();
    short8 af[4], bfr[4];
#pragma unroll
    for (int mt = 0; mt < 4; ++mt)
      af[mt] = *(const short8*)&la[(wm*64 + mt*16 + (lane & 15))*32 + ((lane >> 4)*8)];
#pragma unroll
    for (int nt = 0; nt < 4; ++nt)
      bfr[nt] = *(const short8*)&lb[(wn*64 + nt*16 + (lane & 15))*32 + ((lane >> 4)*8)];
#pragma unroll
    for (int mt = 0; mt < 4; ++mt)
#pragma unroll
      for (int nt = 0; nt < 4; ++nt)
        acc[mt][nt] = __builtin_amdgcn_mfma_f32_16x16x32_bf16(af[mt], bfr[nt], acc[mt][nt], 0,0,0);
    __syncthreads();
  }

  const int col = lane & 15, quad = lane >> 4;
#pragma unroll
  for (int nt = 0; nt < 4; ++nt){
    long n = n0 + wn*64 + nt*16 + col;
    float bias = ldf(b_fc, n, is32);
#pragma unroll
    for (int mt = 0; mt < 4; ++mt){
      int tr0 = wm*64 + mt*16 + quad*4;              // tile row of acc[..][0]
      long m = (long)(tr0 >> 3)*S_ + jt*8 + (tr0 & 7);  // output row b*128+t
      float v0 = acc[mt][nt][0] + bias;
      float v1 = acc[mt][nt][1] + bias;
      float v2 = acc[mt][nt][2] + bias;
      float v3 = acc[mt][nt][3] + bias;
      if (is32){
        float* p = (float*)outv + m*V_ + n;
        __builtin_nontemporal_store(v0, p);
        __builtin_nontemporal_store(v1, p + V_);
        __builtin_nontemporal_store(v2, p + 2L*V_);
        __builtin_nontemporal_store(v3, p + 3L*V_);
      } else {
        u16* p = (u16*)outv + m*V_ + n;
        __builtin_nontemporal_store(f2bf(v0), p);
        __builtin_nontemporal_store(f2bf(v1), p + V_);
        __builtin_nontemporal_store(f2bf(v2), p + 2L*V_);
        __builtin_nontemporal_store(f2bf(v3), p + 3L*V_);
      }
    }
  }
}

// ---------------------------------------------------------------------------
// FALLBACK Phase B (round-5 verbatim, proven): standalone recurrence.
// ---------------------------------------------------------------------------
__global__ __launch_bounds__(256, 1) void k_steps_all(
    const void* __restrict__ W_hh, const float* __restrict__ xg,
    const void* __restrict__ h_in, const void* __restrict__ c_in,
    u16* __restrict__ h_buf, u16* __restrict__ hs,
    const u32* __restrict__ flag, u32* arr, u32* bar_gen)
{
  const int is32 = (int)flag[0];
  const int s    = blockIdx.x;         // 64
  const int tid  = threadIdx.x;
  const int lane = tid & 63;
  const int wv   = tid >> 6;

  __shared__ __align__(16) float part[4][4][16][20];

  short8 wf[4][8];
#pragma unroll
  for (int q = 0; q < 4; ++q){
    const long wrow = (long)(q*H_ + s*16 + (lane & 15))*H_ + wv*256 + ((lane >> 4)*8);
#pragma unroll
    for (int j = 0; j < 8; ++j)
      wf[q][j] = load8(W_hh, wrow + j*32, is32);
  }

  const int eb = tid >> 4;
  const int er = tid & 15;
  const int co = eb*H_ + s*16 + er;
  float c_val = ldf(c_in, co, is32);

  const int arow = (lane & 15)*H_ + wv*256 + ((lane >> 4)*8);
  const float* xg_b = xg + (s*16 + er)*16 + eb;
  u16* hs_b = hs + (long)eb*S_*H_ + s*16 + er;

  {
    float hv0 = ldf(h_in, co, is32);
    u16 hi0 = f2bf(hv0);
    st_dev_u16(h_buf + co,         hi0);
    st_dev_u16(h_buf + B_*H_ + co, f2bf(hv0 - bf2f(hi0)));
  }
  __syncthreads();
  if (tid == 0) st_dev_u32(arr + s*32, 1u);

  for (int t = 0; t < S_; ++t){
    const float* xg_t = xg_b + (long)t*65536;
    float pre0 = xg_t[0], pre1 = xg_t[16384], pre2 = xg_t[32768], pre3 = xg_t[49152];

    const u32 tgen = (u32)(t + 1);
    if (s == 0 && tid < 64){
      u32 iters = 0;
      while (true){
        u32 v = ld_dev_u32(arr + tid*32);
        if (__all((int)(v >= tgen))) break;
        if (++iters > SPIN_CAP) break;
        __builtin_amdgcn_s_sleep(1);
      }
      if (tid == 0) st_dev_u32(bar_gen, tgen);
    } else if (tid == 0){
      u32 iters = 0;
      while (ld_dev_u32(bar_gen) < tgen){
        if (++iters > SPIN_CAP) break;
        __builtin_amdgcn_s_sleep(1);
      }
    }
    __syncthreads();

    const u16* hp = h_buf + (t & 1)*(2*B_*H_) + arow;
    short8 ahi[8], alo[8];
#pragma unroll
    for (int j = 0; j < 8; ++j){
      ahi[j] = ld_frag_dev(hp + j*32);
      alo[j] = ld_frag_dev(hp + B_*H_ + j*32);
    }

    f32x4 acc[4];
#pragma unroll
    for (int q = 0; q < 4; ++q) acc[q] = (f32x4){0.f,0.f,0.f,0.f};
#pragma unroll
    for (int j = 0; j < 8; ++j){
#pragma unroll
      for (int q = 0; q < 4; ++q){
        acc[q] = __builtin_amdgcn_mfma_f32_16x16x32_bf16(ahi[j], wf[q][j], acc[q], 0,0,0);
        acc[q] = __builtin_amdgcn_mfma_f32_16x16x32_bf16(alo[j], wf[q][j], acc[q], 0,0,0);
      }
    }
#pragma unroll
    for (int q = 0; q < 4; ++q)
      *(f32x4*)&part[wv][q][lane & 15][(lane >> 4)*4] = acc[q];
    __syncthreads();

    float p0 = pre0, p1 = pre1, p2 = pre2, p3 = pre3;
#pragma unroll
    for (int w = 0; w < 4; ++w){
      p0 += part[w][0][er][eb];
      p1 += part[w][1][er][eb];
      p2 += part[w][2][er][eb];
      p3 += part[w][3][er][eb];
    }
    float iv = sigm(p0), fv = sigm(p1), gv = tanh_f(p2), ov = sigm(p3);
    c_val = fv*c_val + iv*gv;
    float hv = ov*tanh_f(c_val);
    u16 hi = f2bf(hv);
    u16 lo = f2bf(hv - bf2f(hi));
    const int po = ((t + 1) & 1)*(2*B_*H_);
    st_dev_u16(h_buf + po + co,         hi);
    st_dev_u16(h_buf + po + B_*H_ + co, lo);

    __syncthreads();
    if (tid == 0) st_dev_u32(arr + s*32, (u32)(t + 2));
    hs_b[(long)t*H_] = hi;
  }
}

// ---------------------------------------------------------------------------
// FALLBACK Phase C: standalone logits over 4000 tiles (jt, np) + XCD swizzle.
// ---------------------------------------------------------------------------
__global__ __launch_bounds__(256) void k_logits(
    const u16* __restrict__ hs, const void* __restrict__ W_fc,
    const u16* __restrict__ wcvt, const void* __restrict__ b_fc,
    void* __restrict__ outv, const u32* __restrict__ flag)
{
  const int is32 = (int)flag[0];
  __shared__ __align__(16) u16 la[128*32];
  __shared__ __align__(16) u16 lb[128*32];
  const int lin  = blockIdx.x;
  const int lin2 = (lin & 7)*500 + (lin >> 3);   // bijective (4000 % 8 == 0)
  const int jt = lin2 & 15;
  const int np = lin2 >> 4;
  const u16* Wb = is32 ? wcvt : (const u16*)W_fc;
  logits_tile(hs, Wb, W_fc, b_fc, outv, is32, jt, np, (int)threadIdx.x, la, lb);
}

// ---------------------------------------------------------------------------
// FUSED Phase B+C: 256 WGs cooperative.  WGs 0..63 run the recurrence (round-5
// body; hs stores now agent-scope and drained BEFORE the arrive store, and the
// barrier aggregator mirrors bar_gen into `prog` on a separate line).  WGs
// 64..255 (and producers, once done) pull logits tiles from a global ticket in
// readiness (jt-major) order, each gated on prog >= jt*8+9.  hs chunks are
// immutable after readiness, so consumer L2 caching is safe (first touch is
// always post-readiness; fresh data reaches L3 via the write-through stores
// drained before the arrive that prog transitively publishes).
// ---------------------------------------------------------------------------
__global__ __launch_bounds__(256, 1) void k_fused(
    const void* __restrict__ W_hh, const float* __restrict__ xg,
    const void* __restrict__ h_in, const void* __restrict__ c_in,
    u16* __restrict__ h_buf, u16* __restrict__ hs,
    const u32* __restrict__ flag, u32* arr, u32* bar_gen, u32* prog,
    u32* ticket, const void* __restrict__ W_fc, const u16* __restrict__ wcvt,
    const void* __restrict__ b_fc, void* __restrict__ outv)
{
  const int is32 = (int)flag[0];
  const int s    = blockIdx.x;         // 0..255
  const int tid  = threadIdx.x;

  __shared__ __align__(16) float part[4][4][16][20];
  __shared__ __align__(16) u16 la[128*32];
  __shared__ __align__(16) u16 lb[128*32];
  __shared__ int tks;

  if (s < 64){
    // ---------------- producer: recurrence ----------------
    const int lane = tid & 63;
    const int wv   = tid >> 6;

    short8 wf[4][8];
#pragma unroll
    for (int q = 0; q < 4; ++q){
      const long wrow = (long)(q*H_ + s*16 + (lane & 15))*H_ + wv*256 + ((lane >> 4)*8);
#pragma unroll
      for (int j = 0; j < 8; ++j)
        wf[q][j] = load8(W_hh, wrow + j*32, is32);
    }

    const int eb = tid >> 4;
    const int er = tid & 15;
    const int co = eb*H_ + s*16 + er;
    float c_val = ldf(c_in, co, is32);

    const int arow = (lane & 15)*H_ + wv*256 + ((lane >> 4)*8);
    const float* xg_b = xg + (s*16 + er)*16 + eb;
    u16* hs_b = hs + (long)eb*S_*H_ + s*16 + er;

    {
      float hv0 = ldf(h_in, co, is32);
      u16 hi0 = f2bf(hv0);
      st_dev_u16(h_buf + co,         hi0);
      st_dev_u16(h_buf + B_*H_ + co, f2bf(hv0 - bf2f(hi0)));
    }
    __syncthreads();
    if (tid == 0) st_dev_u32(arr + s*32, 1u);

    for (int t = 0; t < S_; ++t){
      const float* xg_t = xg_b + (long)t*65536;
      float pre0 = xg_t[0], pre1 = xg_t[16384], pre2 = xg_t[32768], pre3 = xg_t[49152];

      const u32 tgen = (u32)(t + 1);
      if (s == 0 && tid < 64){
        u32 iters = 0;
        while (true){
          u32 v = ld_dev_u32(arr + tid*32);
          if (__all((int)(v >= tgen))) break;
          if (++iters > SPIN_CAP) break;
          __builtin_amdgcn_s_sleep(1);
        }
        if (tid == 0){
          st_dev_u32(bar_gen, tgen);
          st_dev_u32(prog, tgen);      // consumer-visible progress mirror
        }
      } else if (tid == 0){
        u32 iters = 0;
        while (ld_dev_u32(bar_gen) < tgen){
          if (++iters > SPIN_CAP) break;
          __builtin_amdgcn_s_sleep(1);
        }
      }
      __syncthreads();

      const u16* hp = h_buf + (t & 1)*(2*B_*H_) + arow;
      short8 ahi[8], alo[8];
#pragma unroll
      for (int j = 0; j < 8; ++j){
        ahi[j] = ld_frag_dev(hp + j*32);
        alo[j] = ld_frag_dev(hp + B_*H_ + j*32);
      }

      f32x4 acc[4];
#pragma unroll
      for (int q = 0; q < 4; ++q) acc[q] = (f32x4){0.f,0.f,0.f,0.f};
#pragma unroll
      for (int j = 0; j < 8; ++j){
#pragma unroll
        for (int q = 0; q < 4; ++q){
          acc[q] = __builtin_amdgcn_mfma_f32_16x16x32_bf16(ahi[j], wf[q][j], acc[q], 0,0,0);
          acc[q] = __builtin_amdgcn_mfma_f32_16x16x32_bf16(alo[j], wf[q][j], acc[q], 0,0,0);
        }
      }
#pragma unroll
      for (int q = 0; q < 4; ++q)
        *(f32x4*)&part[wv][q][lane & 15][(lane >> 4)*4] = acc[q];
      __syncthreads();

      float p0 = pre0, p1 = pre1, p2 = pre2, p3 = pre3;
#pragma unroll
      for (int w = 0; w < 4; ++w){
        p0 += part[w][0][er][eb];
        p1 += part[w][1][er][eb];
        p2 += part[w][2][er][eb];
        p3 += part[w][3][er][eb];
      }
      float iv = sigm(p0), fv = sigm(p1), gv = tanh_f(p2), ov = sigm(p3);
      c_val = fv*c_val + iv*gv;
      float hv = ov*tanh_f(c_val);
      u16 hi = f2bf(hv);
      u16 lo = f2bf(hv - bf2f(hi));
      const int po = ((t + 1) & 1)*(2*B_*H_);
      st_dev_u16(h_buf + po + co,         hi);
      st_dev_u16(h_buf + po + B_*H_ + co, lo);
      st_dev_u16(hs_b + (long)t*H_, hi);   // must drain BEFORE arrive (consumers)

      __syncthreads();                     // vmcnt(0): h + hs at coherence point
      if (tid == 0) st_dev_u32(arr + s*32, (u32)(t + 2));
    }

    // final publish: confirm all WGs posted arrive(S_+1), then prog = S_+1
    if (s == 0){
      if (tid < 64){
        u32 iters = 0;
        while (true){
          u32 v = ld_dev_u32(arr + tid*32);
          if (__all((int)(v >= (u32)(S_ + 1)))) break;
          if (++iters > SPIN_CAP) break;
          __builtin_amdgcn_s_sleep(1);
        }
      }
      __syncthreads();
      if (tid == 0){
        st_dev_u32(bar_gen, (u32)(S_ + 1));
        st_dev_u32(prog,    (u32)(S_ + 1));
      }
    }
  }

  // ---------------- consumer loop (all WGs; producers join at the end) ------
  const u16* Wb = is32 ? wcvt : (const u16*)W_fc;
  for (;;){
    __syncthreads();                       // protect tks reuse
    if (tid == 0)
      tks = (int)__hip_atomic_fetch_add(ticket, 1u, __ATOMIC_RELAXED, __HIP_MEMORY_SCOPE_AGENT);
    __syncthreads();
    const int tile = tks;
    if (tile >= 16*250) break;
    const int jt = tile / 250;
    const int np = tile - jt*250;
    if (tid == 0){
      const u32 need = (u32)(jt*8 + 9);    // steps 0..jt*8+7 complete
      u32 iters = 0;
      while (ld_dev_u32(prog) < need){
        if (++iters > SPIN_CAP) break;
        __builtin_amdgcn_s_sleep(32);      // long backoff: off the hot lines
      }
    }
    __syncthreads();
    logits_tile(hs, Wb, W_fc, b_fc, outv, is32, jt, np, tid, la, lb);
  }
}

// ---------------------------------------------------------------------------
extern "C" void kernel_launch(void* const* d_in, const int* in_sizes, int n_in,
                              void* d_out, int out_size, void* d_ws, size_t ws_size,
                              hipStream_t stream)
{
  (void)in_sizes; (void)n_in; (void)out_size;
  const int*  tgt  = (const int*)d_in[0];
  const void* h0   = d_in[1];
  const void* c0   = d_in[2];
  const void* emb  = d_in[3];
  const void* W_ih = d_in[4];
  const void* W_hh = d_in[5];
  const void* b_ih = d_in[6];
  const void* b_hh = d_in[7];
  const void* W_fc = d_in[8];
  const void* b_fc = d_in[9];

  char* ws = (char*)d_ws;
  u16*   hs      = (u16*)(ws);             // [16][128][1024] bf16  = 4,194,304 B
  u16*   h_buf   = (u16*)(ws + 4194304);   // [2][2][16][1024] bf16 =   131,072 B
  u32*   flag    = (u32*)(ws + 4325376);   // 128B line
  u32*   arr     = (u32*)(ws + 4325504);   // 64 flags x 128B       =     8,192 B
  u32*   bar_gen = (u32*)(ws + 4333696);   // 128B line
  u32*   prog    = (u32*)(ws + 4333824);   // 128B line
  u32*   ticket  = (u32*)(ws + 4333952);   // 128B line
  const size_t WCVT_OFF = 4334080;                     // 65,536,000 B
  const size_t XG_OFF   = WCVT_OFF + 65536000u;        // 33,554,432 B
  const size_t NEED_FB  = WCVT_OFF + 65536000u;        // fallback w/ wcvt
  const size_t NEED_OV  = XG_OFF   + 33554432u;        // fused (xg in ws)

  u16* wcvt = (ws_size >= NEED_FB) ? (u16*)(ws + WCVT_OFF) : (u16*)0;
  const int overlap = (ws_size >= NEED_OV);

  k_detect<<<1, 64, 0, stream>>>((const u32*)h0, flag, arr, bar_gen, prog, ticket);

  if (overlap){
    float* xg = (float*)(ws + XG_OFF);     // d_out is written concurrently
    dim3 gA(64, 32);
    k_xg<<<gA, 256, 0, stream>>>(tgt, emb, W_ih, b_ih, b_hh, xg, flag);
    k_wfc<<<2048, 256, 0, stream>>>(W_fc, wcvt, flag);

    void* args[15];
    u16* hb = h_buf;  u16* hsp = hs;
    args[0]  = (void*)&W_hh;  args[1]  = (void*)&xg;     args[2]  = (void*)&h0;
    args[3]  = (void*)&c0;    args[4]  = (void*)&hb;     args[5]  = (void*)&hsp;
    args[6]  = (void*)&flag;  args[7]  = (void*)&arr;    args[8]  = (void*)&bar_gen;
    args[9]  = (void*)&prog;  args[10] = (void*)&ticket; args[11] = (void*)&W_fc;
    args[12] = (void*)&wcvt;  args[13] = (void*)&b_fc;   args[14] = (void*)&d_out;
    hipLaunchCooperativeKernel((const void*)k_fused, dim3(256), dim3(256),
                               args, 0, stream);
  } else {
    // round-5 structure: xg in d_out (dead before k_logits overwrites it)
    float* xg = (float*)d_out;
    dim3 gA(64, 32);
    k_xg<<<gA, 256, 0, stream>>>(tgt, emb, W_ih, b_ih, b_hh, xg, flag);
    if (wcvt) k_wfc<<<2048, 256, 0, stream>>>(W_fc, wcvt, flag);

    u16* hb = h_buf;  u16* hsp = hs;
    void* args[9];
    args[0] = (void*)&W_hh; args[1] = (void*)&xg;   args[2] = (void*)&h0;
    args[3] = (void*)&c0;   args[4] = (void*)&hb;   args[5] = (void*)&hsp;
    args[6] = (void*)&flag; args[7] = (void*)&arr;  args[8] = (void*)&bar_gen;
    hipLaunchCooperativeKernel((const void*)k_steps_all, dim3(64), dim3(256),
                               args, 0, stream);

    dim3 gC(4000);
    k_logits<<<gC, 256, 0, stream>>>(hs, W_fc, wcvt, b_fc, d_out, flag);
  }
}